// Round 4
// baseline (705.126 us; speedup 1.0000x reference)
//
#include <hip/hip_runtime.h>

#define N_NODES 8192
#define N_EDGES 4096
#define F_INS   256
#define HEADS   8
#define DOUT    64
#define HDIM    512   // HEADS*DOUT
#define CCOMB   1024  // 2*HDIM (both batches as columns)
#define BATCH   2

typedef __bf16 bf16x8 __attribute__((ext_vector_type(8)));
typedef __bf16 bf16x4 __attribute__((ext_vector_type(4)));
typedef float  f32x4  __attribute__((ext_vector_type(4)));

// async 16B global->LDS (wave-uniform LDS base + lane*16)
__device__ __forceinline__ void gld_lds16(const __bf16* g, __bf16* l) {
    __builtin_amdgcn_global_load_lds(
        (const __attribute__((address_space(1))) void*)g,
        (__attribute__((address_space(3))) void*)l, 16, 0, 0);
}

// ---------- fused: H fp32 -> Hb/HbT bf16  +  plog partials (fp32 exact, atomic-free) ----
// grid: (E/128, N/256), 256 threads. Reads H once, float4-vectorized.
// 8 groups of 32 nodes, double-buffered LDS transpose tile, ONE barrier per group.
// v3: H loads software-pipelined TWO groups ahead (vA/vB double reg buffers,
// x2-unrolled loop) so loaded-HBM latency hides under the previous group's
// compute + barrier instead of serializing every group.
__launch_bounds__(256, 4)
__global__ void convert_H_logits_kernel(const float* __restrict__ H,
                                        const float* __restrict__ av,
                                        __bf16* __restrict__ Hb,
                                        __bf16* __restrict__ HbT,
                                        float* __restrict__ plog) {
    __shared__ __align__(16) char smem[33280];
    float* lav = (float*)smem;                                   // [256][16] = 16 KB
    __bf16 (*tile)[32][132] = (__bf16(*)[32][132])(smem + 16384); // [2][32][132] = 16.5 KB
    float* red = (float*)smem;                                   // [4][16][128] = 32 KB overlay

    int t = threadIdx.x;
    int e0 = blockIdx.x * 128;
    int n0 = blockIdx.y * 256;
    int equad = t & 31, r0 = t >> 5;
    int lane = t & 63, wv = t >> 6;

    // stage lav[n][q]: q = b*8+h
    for (int p = t; p < 4096; p += 256) {
        int n = p >> 4, q = p & 15, b = q >> 3, h = q & 7;
        lav[p] = av[(size_t)b * (N_NODES * 8) + (size_t)(n0 + n) * 8 + h];
    }

    const float* hbase = H + (size_t)n0 * N_EDGES + e0 + equad * 4;
    __bf16* hb_base = Hb + (size_t)n0 * N_EDGES + e0 + equad * 4;

    f32x4 acc[4][4] = {};  // [ec][qq], components = qi

    float4 vA[4], vB[4];
#define LOAD_GRP(g, v)                                                        \
    {                                                                         \
        _Pragma("unroll")                                                     \
        for (int k = 0; k < 4; ++k) {                                         \
            int n = (g) * 32 + r0 + 8 * k;                                    \
            (v)[k] = *(const float4*)(hbase + (size_t)n * N_EDGES);           \
        }                                                                     \
    }
#define TR_OUT(g)                                                             \
    {                                                                         \
        int pb = (g) & 1, pnb = (g) * 32;                                     \
        _Pragma("unroll")                                                     \
        for (int s = 0; s < 2; ++s) {                                         \
            int id = s * 256 + t;                                             \
            int er = id >> 2, oct = id & 3;                                   \
            bf16x8 val;                                                       \
            _Pragma("unroll")                                                 \
            for (int j = 0; j < 8; ++j) val[j] = tile[pb][oct * 8 + j][er];   \
            *(bf16x8*)(HbT + (size_t)(e0 + er) * N_NODES + n0 + pnb +         \
                       oct * 8) = val;                                        \
        }                                                                     \
    }
#define COMP(g, v)                                                            \
    {                                                                         \
        int buf = (g) & 1;                                                    \
        _Pragma("unroll")                                                     \
        for (int k = 0; k < 4; ++k) {                                         \
            int n = (g) * 32 + r0 + 8 * k;                                    \
            const f32x4* lrow = (const f32x4*)&lav[n * 16];                   \
            float4 vv = (v)[k];                                               \
            _Pragma("unroll")                                                 \
            for (int qq = 0; qq < 4; ++qq) {                                  \
                f32x4 l = lrow[qq];                                           \
                acc[0][qq] += l * vv.x;                                       \
                acc[1][qq] += l * vv.y;                                       \
                acc[2][qq] += l * vv.z;                                       \
                acc[3][qq] += l * vv.w;                                       \
            }                                                                 \
            bf16x4 hb;                                                        \
            hb.x = (__bf16)vv.x; hb.y = (__bf16)vv.y;                         \
            hb.z = (__bf16)vv.z; hb.w = (__bf16)vv.w;                         \
            *(bf16x4*)(hb_base + (size_t)n * N_EDGES) = hb;                   \
            *(bf16x4*)&tile[buf][r0 + 8 * k][equad * 4] = hb;                 \
        }                                                                     \
    }

    // prologue: groups 0 and 1 in flight before first barrier
    LOAD_GRP(0, vA);
    LOAD_GRP(1, vB);
    __syncthreads();  // lav ready

    for (int g = 0; g < 8; g += 2) {
        // phase A: group g (vA)
        if (g > 0) TR_OUT(g - 1);
        COMP(g, vA);
        if (g + 2 < 8) LOAD_GRP(g + 2, vA);
        __syncthreads();
        // phase B: group g+1 (vB)
        TR_OUT(g);
        COMP(g + 1, vB);
        if (g + 3 < 8) LOAD_GRP(g + 3, vB);
        __syncthreads();
    }
    TR_OUT(7);
#undef LOAD_GRP
#undef TR_OUT
#undef COMP

    // logits reduce: intra-wave (r0 pairs) via shfl_xor(32)
#pragma unroll
    for (int ec = 0; ec < 4; ++ec)
#pragma unroll
        for (int qq = 0; qq < 4; ++qq)
#pragma unroll
            for (int qi = 0; qi < 4; ++qi)
                acc[ec][qq][qi] += __shfl_xor(acc[ec][qq][qi], 32, 64);

    __syncthreads();  // all tile/lav reads done before red overlay
    if (lane < 32) {
        // red[wv][q][el]: write f32x4 over ec at el = equad*4 -> conflict-free b128
#pragma unroll
        for (int qq = 0; qq < 4; ++qq)
#pragma unroll
            for (int qi = 0; qi < 4; ++qi) {
                f32x4 tmp = {acc[0][qq][qi], acc[1][qq][qi],
                             acc[2][qq][qi], acc[3][qq][qi]};
                *(f32x4*)&red[wv * 2048 + (qq * 4 + qi) * 128 + equad * 4] = tmp;
            }
    }
    __syncthreads();
#pragma unroll
    for (int s = 0; s < 8; ++s) {
        int id = s * 256 + t;  // 2048 = 16 q x 128 el
        int q = id >> 7, el = id & 127;
        float sum = red[q * 128 + el] + red[2048 + q * 128 + el] +
                    red[4096 + q * 128 + el] + red[6144 + q * 128 + el];
        plog[((size_t)blockIdx.y * 16 + q) * N_EDGES + e0 + el] = sum;
    }
}

// ---------- logits[q][e] = sum_nb plog[nb][q][e] ----------
__launch_bounds__(256)
__global__ void reduce_logits_kernel(const float* __restrict__ plog,
                                     float* __restrict__ logits) {
    int id = blockIdx.x * 256 + threadIdx.x;  // 65536 = 16 q x 4096 e
    int q = id >> 12, e = id & 4095;
    float s = 0.f;
#pragma unroll
    for (int nb = 0; nb < 32; ++nb)
        s += plog[((size_t)nb * 16 + q) * N_EDGES + e];
    logits[(size_t)q * N_EDGES + e] = s;
}

// ---------- W (fp32 F_INS x HDIM) -> WbT (bf16 HDIM x F_INS) ----------
__launch_bounds__(256)
__global__ void wbt_kernel(const float* __restrict__ W, __bf16* __restrict__ WbT) {
    int i = blockIdx.x * 256 + threadIdx.x;  // 512*256 = 131072
    int c = i >> 8, f = i & 255;
    WbT[i] = (__bf16)W[(size_t)f * HDIM + c];
}

// ---------- Wa[f][h] = sum_d W[f][h*64+d] * a[d]  (fp32, exact path for av) ----------
__launch_bounds__(256)
__global__ void wa_kernel(const float* __restrict__ W, const float* __restrict__ a,
                          float* __restrict__ Wa) {
    int i = blockIdx.x * 256 + threadIdx.x;  // 2048
    if (i >= F_INS * HEADS) return;
    int f = i >> 3, h = i & 7;
    float s = 0.f;
#pragma unroll 8
    for (int d = 0; d < DOUT; ++d) s += W[(size_t)f * HDIM + h * DOUT + d] * a[d];
    Wa[i] = s;
}

// ---------- fused: av = leaky_relu(x . Wa) fp32  +  xb = bf16(x) ----------
__launch_bounds__(256)
__global__ void av_kernel(const float* __restrict__ x, const float* __restrict__ Wa,
                          float* __restrict__ av, __bf16* __restrict__ xb) {
    __shared__ float lx[32][257];
    __shared__ float lwa[F_INS * HEADS];
    int t = threadIdx.x;
    size_t row0 = (size_t)blockIdx.x * 32;  // rows = b*8192+n, 16384 total
    for (int p = t; p < F_INS * HEADS; p += 256) lwa[p] = Wa[p];
#pragma unroll
    for (int p = 0; p < 32; ++p) {
        float v = x[(row0 + p) * F_INS + t];
        lx[p][t] = v;
        xb[(row0 + p) * F_INS + t] = (__bf16)v;
    }
    __syncthreads();
    int r = t >> 3, h = t & 7;
    float acc = 0.f;
#pragma unroll 8
    for (int f = 0; f < F_INS; ++f) acc += lx[r][f] * lwa[f * 8 + h];
    av[(row0 + r) * 8 + h] = acc > 0.f ? acc : 0.2f * acc;
}

// ---------- softmax over e for each of 16 (b,h) rows, in place ----------
__launch_bounds__(256)
__global__ void softmax_kernel(float* __restrict__ logits) {
    __shared__ float red[4];
    __shared__ float reds[4];
    int t = threadIdx.x;
    float* row = logits + (size_t)blockIdx.x * N_EDGES;
    float mx = -1e30f;
    for (int i = t; i < N_EDGES; i += 256) mx = fmaxf(mx, row[i]);
#pragma unroll
    for (int o = 32; o > 0; o >>= 1) mx = fmaxf(mx, __shfl_xor(mx, o, 64));
    if ((t & 63) == 0) red[t >> 6] = mx;
    __syncthreads();
    mx = fmaxf(fmaxf(red[0], red[1]), fmaxf(red[2], red[3]));
    float s = 0.f;
    for (int i = t; i < N_EDGES; i += 256) {
        float v = expf(row[i] - mx);
        row[i] = v;
        s += v;
    }
#pragma unroll
    for (int o = 32; o > 0; o >>= 1) s += __shfl_xor(s, o, 64);
    if ((t & 63) == 0) reds[t >> 6] = s;
    __syncthreads();
    float inv = 1.0f / (reds[0] + reds[1] + reds[2] + reds[3]);
    for (int i = t; i < N_EDGES; i += 256) row[i] *= inv;
}

// ---------- 128x128 bf16 MFMA GEMM (m97 structure) — used only for the small K=256
// WhbT GEMM. MODE 0: store bf16 to outB[gm*ldo+gc] (+out_z per z).
template <int MODE>
__launch_bounds__(256, 4)
__global__ void gemm_bt(const __bf16* __restrict__ A, const __bf16* __restrict__ BT,
                        int lda, int ldbt, int K,
                        size_t a_bz, size_t bt_bz, size_t out_z,
                        __bf16* __restrict__ outB, int ldo,
                        float* __restrict__ outF) {
    __shared__ __bf16 AsF[8192];
    __shared__ __bf16 BsF[8192];
    int t = threadIdx.x;
    int bz = blockIdx.z;
    A  += (size_t)bz * a_bz;
    BT += (size_t)bz * bt_bz;
    if (MODE == 0) outB += (size_t)bz * out_z;
    if (MODE == 1) outF += (size_t)bz * out_z;
    size_t m0 = (size_t)blockIdx.y * 128;
    size_t n0 = (size_t)blockIdx.x * 128;

    int lane = t & 63, wv = t >> 6;
    int ln = lane & 15, lk = lane >> 4;

    const __bf16* pA[4]; const __bf16* pB[4];
    __bf16* lA[4]; __bf16* lB[4];
#pragma unroll
    for (int p = 0; p < 4; ++p) {
        int bid = wv * 4 + p;
        int mb = bid >> 1, kb = bid & 1;
        pA[p] = A + (m0 + mb * 16 + ln) * (size_t)lda + kb * 32 + lk * 8;
        pB[p] = BT + (n0 + mb * 16 + ln) * (size_t)ldbt + kb * 32 + lk * 8;
        lA[p] = &AsF[bid * 512];
        lB[p] = &BsF[bid * 512];
    }

    int wm16 = (wv & 1) * 4, wn16 = (wv >> 1) * 4;
    f32x4 acc[4][4] = {};

    for (int k0 = 0; k0 < K; k0 += 64) {
        __syncthreads();
#pragma unroll
        for (int p = 0; p < 4; ++p) gld_lds16(pA[p] + k0, lA[p]);
#pragma unroll
        for (int p = 0; p < 4; ++p) gld_lds16(pB[p] + k0, lB[p]);
        __syncthreads();
#pragma unroll
        for (int ksb = 0; ksb < 2; ++ksb) {
            bf16x8 af[4], bfr[4];
#pragma unroll
            for (int i = 0; i < 4; ++i)
                af[i] = *(const bf16x8*)&AsF[((wm16 + i) * 2 + ksb) * 512 + lane * 8];
#pragma unroll
            for (int j = 0; j < 4; ++j)
                bfr[j] = *(const bf16x8*)&BsF[((wn16 + j) * 2 + ksb) * 512 + lane * 8];
#pragma unroll
            for (int i = 0; i < 4; ++i)
#pragma unroll
                for (int j = 0; j < 4; ++j)
                    acc[i][j] = __builtin_amdgcn_mfma_f32_16x16x32_bf16(
                        af[i], bfr[j], acc[i][j], 0, 0, 0);
        }
    }

    int wm = (wv & 1) * 64, wn = (wv >> 1) * 64;
#pragma unroll
    for (int i = 0; i < 4; ++i)
#pragma unroll
        for (int j = 0; j < 4; ++j)
#pragma unroll
            for (int rg = 0; rg < 4; ++rg) {
                int gm = (int)m0 + wm + i * 16 + lk * 4 + rg;
                int gc = (int)n0 + wn + j * 16 + ln;
                float v = acc[i][j][rg];
                if (MODE == 0) {
                    outB[(size_t)gm * ldo + gc] = (__bf16)v;
                } else if (MODE == 1) {
                    outF[(size_t)gm * ldo + gc] = v;
                } else {
                    outF[(size_t)(gc >> 9) * ((size_t)N_NODES * HDIM) +
                         (size_t)gm * HDIM + (gc & 511)] = v;
                }
            }
}

// ---------- 256x256 deep-pipelined bf16 GEMM ----------
// BK=32, 8 waves (512 thr), 4-deep LDS ring buffer (4 x 32 KB = 128 KB), staging
// issued 3 K-tiles ahead via global_load_lds, counted s_waitcnt vmcnt(8) + raw
// s_barrier (T3/T4), setprio around MFMA cluster (T5). Fragment-major LDS.
// C[m][n] = sum_k A[m][k]*BT[n][k], fp32 plain store outF[gm*ldo+gc] (+out_z per z).
// Requires K % 32 == 0 and K >= 128 (NT >= 4).
// SWZ=1: XCD-aware remap hardcoded for grid (4,32,2).
template <int SWZ>
__launch_bounds__(512, 2)
__global__ void gemm256(const __bf16* __restrict__ A, const __bf16* __restrict__ BT,
                        int lda, int ldbt, int K,
                        size_t a_bz, size_t bt_bz, size_t out_z,
                        float* __restrict__ outF, int ldo) {
    __shared__ __bf16 lds[4 * 32 * 512];  // [buf 0..3][frag 0..31][512]; frags 0-15=A, 16-31=B
    int bx, by, bz;
    if (SWZ) {
        int g = (int)blockIdx.x + 4 * ((int)blockIdx.y + 32 * (int)blockIdx.z);
        int xcd = g & 7, j = g >> 3;
        int l = (j & 3) + 4 * xcd + 32 * (j >> 2);
        bx = l & 3; by = (l >> 2) & 31; bz = l >> 7;
    } else {
        bx = blockIdx.x; by = blockIdx.y; bz = blockIdx.z;
    }
    A    += (size_t)bz * a_bz;
    BT   += (size_t)bz * bt_bz;
    outF += (size_t)bz * out_z;
    size_t m0 = (size_t)by * 256;
    size_t n0 = (size_t)bx * 256;

    int t = threadIdx.x;
    int lane = t & 63, wv = t >> 6;     // 8 waves
    int ln = lane & 15, lk = lane >> 4;

    int fw = wv * 2;
    const __bf16* gA0 = A + (m0 + fw * 16 + ln) * (size_t)lda + lk * 8;
    const __bf16* gA1 = gA0 + 16 * (size_t)lda;
    const __bf16* gB0 = BT + (n0 + fw * 16 + ln) * (size_t)ldbt + lk * 8;
    const __bf16* gB1 = gB0 + 16 * (size_t)ldbt;

    int NT = K >> 5;  // K-tiles of 32

    for (int tt = 0; tt < 3; ++tt) {
        __bf16* d = &lds[tt * 16384];
        gld_lds16(gA0 + tt * 32, d + fw * 512);
        gld_lds16(gA1 + tt * 32, d + (fw + 1) * 512);
        gld_lds16(gB0 + tt * 32, d + (16 + fw) * 512);
        gld_lds16(gB1 + tt * 32, d + (16 + fw + 1) * 512);
    }
    asm volatile("s_waitcnt vmcnt(8)" ::: "memory");  // tile 0 landed; 1,2 in flight
    __builtin_amdgcn_s_barrier();
    __builtin_amdgcn_sched_barrier(0);

    f32x4 acc[8][4] = {};
    int wmf = (wv >> 2) * 8;
    int wnf = (wv & 3) * 4;

    auto compute = [&](int tl) {
        const __bf16* buf = &lds[(tl & 3) * 16384];
        bf16x8 af[8], bfr[4];
#pragma unroll
        for (int i = 0; i < 8; ++i)
            af[i] = *(const bf16x8*)(buf + (wmf + i) * 512 + lane * 8);
#pragma unroll
        for (int j = 0; j < 4; ++j)
            bfr[j] = *(const bf16x8*)(buf + (16 + wnf + j) * 512 + lane * 8);
        __builtin_amdgcn_s_setprio(1);
#pragma unroll
        for (int i = 0; i < 8; ++i)
#pragma unroll
            for (int j = 0; j < 4; ++j)
                acc[i][j] = __builtin_amdgcn_mfma_f32_16x16x32_bf16(
                    af[i], bfr[j], acc[i][j], 0, 0, 0);
        __builtin_amdgcn_s_setprio(0);
    };

    for (int tl = 0; tl < NT - 3; ++tl) {
        __bf16* d = &lds[((tl + 3) & 3) * 16384];
        int off = (tl + 3) * 32;
        gld_lds16(gA0 + off, d + fw * 512);
        gld_lds16(gA1 + off, d + (fw + 1) * 512);
        gld_lds16(gB0 + off, d + (16 + fw) * 512);
        gld_lds16(gB1 + off, d + (16 + fw + 1) * 512);
        compute(tl);
        asm volatile("s_waitcnt vmcnt(8)" ::: "memory");
        __builtin_amdgcn_s_barrier();
        __builtin_amdgcn_sched_barrier(0);
    }
    compute(NT - 3);
    asm volatile("s_waitcnt vmcnt(4)" ::: "memory");
    __builtin_amdgcn_s_barrier();
    __builtin_amdgcn_sched_barrier(0);
    compute(NT - 2);
    asm volatile("s_waitcnt vmcnt(0)" ::: "memory");
    __builtin_amdgcn_s_barrier();
    __builtin_amdgcn_sched_barrier(0);
    compute(NT - 1);

    int wm = (wv >> 2) * 128, wn = (wv & 3) * 64;
#pragma unroll
    for (int i = 0; i < 8; ++i)
#pragma unroll
        for (int j = 0; j < 4; ++j)
#pragma unroll
            for (int rg = 0; rg < 4; ++rg) {
                int gm = (int)m0 + wm + i * 16 + lk * 4 + rg;
                int gc = (int)n0 + wn + j * 16 + ln;
                outF[(size_t)gm * ldo + gc] = acc[i][j][rg];
            }
}

// ---------- mwT = bf16( (slab0+slab1+slab2+slab3) * ae ) ----------
__launch_bounds__(256)
__global__ void scale1_kernel(const float* __restrict__ acc1, const float* __restrict__ ae,
                              __bf16* __restrict__ mwT) {
    int i = blockIdx.x * 256 + threadIdx.x;  // float4 index, 1M total
    size_t base = (size_t)i * 4;
    int c = (int)(base >> 12);
    int e = (int)(base & 4095);
    const size_t slab = (size_t)CCOMB * N_EDGES / 4;  // float4 units
    float4 s0 = ((const float4*)acc1)[i];
    float4 s1 = ((const float4*)acc1)[i + slab];
    float4 s2 = ((const float4*)acc1)[i + 2 * slab];
    float4 s3 = ((const float4*)acc1)[i + 3 * slab];
    float4 a4 = *(const float4*)(ae + ((size_t)(c >> 6) << 12) + e);
    bf16x4 o;
    o.x = (__bf16)((s0.x + s1.x + s2.x + s3.x) * a4.x);
    o.y = (__bf16)((s0.y + s1.y + s2.y + s3.y) * a4.y);
    o.z = (__bf16)((s0.z + s1.z + s2.z + s3.z) * a4.z);
    o.w = (__bf16)((s0.w + s1.w + s2.w + s3.w) * a4.w);
    ((bf16x4*)mwT)[i] = o;
}

// ---------- out[b][n][hd] = slab0[n][c] + slab1[n][c],  c = b*512+hd ----------
__launch_bounds__(256)
__global__ void reduce2_kernel(const float* __restrict__ s, float* __restrict__ out) {
    int i = blockIdx.x * 256 + threadIdx.x;      // float4 units: 8192*1024/4
    size_t base = (size_t)i * 4;
    int m = (int)(base >> 10);
    int c = (int)(base & 1023);
    const size_t slab = (size_t)N_NODES * CCOMB / 4;  // float4 units
    float4 a = ((const float4*)s)[i];
    float4 b = ((const float4*)s)[i + slab];
    float4 o;
    o.x = a.x + b.x; o.y = a.y + b.y; o.z = a.z + b.z; o.w = a.w + b.w;
    *(float4*)&out[(size_t)(c >> 9) * ((size_t)N_NODES * HDIM) +
                   (size_t)m * HDIM + (c & 511)] = o;
}

extern "C" void kernel_launch(void* const* d_in, const int* in_sizes, int n_in,
                              void* d_out, int out_size, void* d_ws, size_t ws_size,
                              hipStream_t stream) {
    const float* x = (const float*)d_in[0];
    const float* H = (const float*)d_in[1];
    const float* W = (const float*)d_in[2];
    const float* a = (const float*)d_in[3];
    float* out = (float*)d_out;

    // workspace carve-up (~235 MB)
    char* p = (char*)d_ws;
    __bf16* Hb   = (__bf16*)p; p += (size_t)N_NODES * N_EDGES * 2;   // 67.1 MB
    __bf16* HbT  = (__bf16*)p; p += (size_t)N_EDGES * N_NODES * 2;   // 67.1 MB
    __bf16* xb   = (__bf16*)p; p += (size_t)BATCH * N_NODES * F_INS * 2; // 8.4 MB
    __bf16* WbT  = (__bf16*)p; p += (size_t)HDIM * F_INS * 2;        // 0.26 MB
    __bf16* WhbT = (__bf16*)p; p += (size_t)CCOMB * N_NODES * 2;     // 16.8 MB
    __bf16* mwT  = (__bf16*)p; p += (size_t)CCOMB * N_EDGES * 2;     // 8.4 MB
    float*  Wa   = (float*)p;  p += (size_t)F_INS * HEADS * 4;
    float*  av   = (float*)p;  p += (size_t)BATCH * N_NODES * HEADS * 4;
    float*  ae   = (float*)p;  p += (size_t)16 * N_EDGES * 4;        // logits->softmax in place
    float*  acc1 = (float*)p;  p += (size_t)4 * CCOMB * N_EDGES * 4; // 67.1 MB: 4 fp32 slabs
    // plog (32 nb x 16 q x 4096 e fp32 = 8 MB) overlays acc1: its lifetime
    // (convert_H -> reduce_logits) ends before gemm256<0> first writes acc1.
    float*  plog = acc1;

    wbt_kernel<<<dim3(HDIM * F_INS / 256), 256, 0, stream>>>(W, WbT);
    wa_kernel<<<dim3(8), 256, 0, stream>>>(W, a, Wa);
    av_kernel<<<dim3(BATCH * N_NODES / 32), 256, 0, stream>>>(x, Wa, av, xb);
    convert_H_logits_kernel<<<dim3(N_EDGES / 128, N_NODES / 256), 256, 0, stream>>>(
        H, av, Hb, HbT, plog);
    reduce_logits_kernel<<<dim3(256), 256, 0, stream>>>(plog, ae);
    softmax_kernel<<<dim3(16), 256, 0, stream>>>(ae);

    // WhbT[b*512+c][n] = sum_f WbT[c][f] * xb[b][n][f]   (K=256, m97 structure is fine)
    gemm_bt<0><<<dim3(64, 4, 2), 256, 0, stream>>>(
        WbT, xb, F_INS, F_INS, F_INS,
        0, (size_t)N_NODES * F_INS, (size_t)HDIM * N_NODES,
        WhbT, N_NODES, nullptr);

    // acc1 slab z: [c][e] = sum over n-slab of WhbT[c][n]*HbT[e][n]
    // 256x256 deep pipeline; K=8192 -> 4 slabs of 2048; 16*4*4 = 256 blocks = 1/CU
    gemm256<0><<<dim3(16, 4, 4), 512, 0, stream>>>(
        WhbT, HbT, N_NODES, N_NODES, 2048,
        2048, 2048, (size_t)CCOMB * N_EDGES,
        acc1, N_EDGES);

    // mwT[c][e] = bf16( (sum of 4 slabs) * ae[c>>6][e] )
    scale1_kernel<<<dim3(CCOMB * N_EDGES / 4 / 256), 256, 0, stream>>>(acc1, ae, mwT);

    // out-slab z (into acc1, now free): [n][c] = sum over e-slab of Hb[n][e]*mwT[c][e]
    // K=4096 -> 2 slabs of 2048; 4*32*2 = 256 blocks = 1/CU; XCD swizzle for A-panel reuse
    gemm256<1><<<dim3(4, 32, 2), 512, 0, stream>>>(
        Hb, mwT, N_EDGES, N_EDGES, 2048,
        2048, 2048, (size_t)N_NODES * CCOMB,
        acc1, CCOMB);

    // out[b][n][hd] = slab0 + slab1 (scatter to final layout)
    reduce2_kernel<<<dim3(N_NODES * CCOMB / 4 / 256), 256, 0, stream>>>(acc1, out);
}

// Round 6
// 475.979 us; speedup vs baseline: 1.4814x; 1.4814x over previous
//
#include <hip/hip_runtime.h>

#define N_NODES 8192
#define N_EDGES 4096
#define F_INS   256
#define HEADS   8
#define DOUT    64
#define HDIM    512   // HEADS*DOUT
#define CCOMB   1024  // 2*HDIM (both batches as columns)
#define BATCH   2

typedef __bf16 bf16x8 __attribute__((ext_vector_type(8)));
typedef __bf16 bf16x4 __attribute__((ext_vector_type(4)));
typedef float  f32x4  __attribute__((ext_vector_type(4)));

// async 16B global->LDS (wave-uniform LDS base + lane*16)
__device__ __forceinline__ void gld_lds16(const __bf16* g, __bf16* l) {
    __builtin_amdgcn_global_load_lds(
        (const __attribute__((address_space(1))) void*)g,
        (__attribute__((address_space(3))) void*)l, 16, 0, 0);
}

// ---------- fused: H fp32 -> Hb/HbT bf16  +  plog partials (fp32 exact, atomic-free) ----
// grid: (E/128, N/256), 256 threads. Reads H once, float4-vectorized.
// 8 groups of 32 nodes, double-buffered LDS transpose tile, ONE barrier per group.
// (round-3 verified version; the reg-double-buffer pipeline variant spilled to
// scratch and quadrupled HBM traffic — do not reintroduce.)
__launch_bounds__(256, 4)
__global__ void convert_H_logits_kernel(const float* __restrict__ H,
                                        const float* __restrict__ av,
                                        __bf16* __restrict__ Hb,
                                        __bf16* __restrict__ HbT,
                                        float* __restrict__ plog) {
    __shared__ __align__(16) char smem[33280];
    float* lav = (float*)smem;                                   // [256][16] = 16 KB
    __bf16 (*tile)[32][132] = (__bf16(*)[32][132])(smem + 16384); // [2][32][132] = 16.5 KB
    float* red = (float*)smem;                                   // [4][16][128] = 32 KB overlay

    int t = threadIdx.x;
    int e0 = blockIdx.x * 128;
    int n0 = blockIdx.y * 256;
    int equad = t & 31, r0 = t >> 5;
    int lane = t & 63, wv = t >> 6;

    // stage lav[n][q]: q = b*8+h
    for (int p = t; p < 4096; p += 256) {
        int n = p >> 4, q = p & 15, b = q >> 3, h = q & 7;
        lav[p] = av[(size_t)b * (N_NODES * 8) + (size_t)(n0 + n) * 8 + h];
    }

    const float* hbase = H + (size_t)n0 * N_EDGES + e0 + equad * 4;
    __bf16* hb_base = Hb + (size_t)n0 * N_EDGES + e0 + equad * 4;

    f32x4 acc[4][4] = {};  // [ec][qq], components = qi

    __syncthreads();  // lav ready

    float4 v[4];
    for (int g = 0; g < 8; ++g) {
        int nb = g * 32;
        // issue this group's 4 float4 loads (independent of LDS)
#pragma unroll
        for (int k = 0; k < 4; ++k) {
            int n = nb + r0 + 8 * k;
            v[k] = *(const float4*)(hbase + (size_t)n * N_EDGES);
        }
        // transpose-out of group g-1 from tile[(g-1)&1] (overlaps load latency)
        if (g > 0) {
            int pb = (g - 1) & 1, pnb = (g - 1) * 32;
#pragma unroll
            for (int s = 0; s < 2; ++s) {
                int id = s * 256 + t;
                int er = id >> 2, oct = id & 3;
                bf16x8 val;
#pragma unroll
                for (int j = 0; j < 8; ++j) val[j] = tile[pb][oct * 8 + j][er];
                *(bf16x8*)(HbT + (size_t)(e0 + er) * N_NODES + n0 + pnb + oct * 8) = val;
            }
        }
        // compute: FMA into acc, convert, Hb store, tile write
        int buf = g & 1;
#pragma unroll
        for (int k = 0; k < 4; ++k) {
            int n = nb + r0 + 8 * k;
            const f32x4* lrow = (const f32x4*)&lav[n * 16];
            float4 vv = v[k];
#pragma unroll
            for (int qq = 0; qq < 4; ++qq) {
                f32x4 l = lrow[qq];
                acc[0][qq] += l * vv.x;
                acc[1][qq] += l * vv.y;
                acc[2][qq] += l * vv.z;
                acc[3][qq] += l * vv.w;
            }
            bf16x4 hb;
            hb.x = (__bf16)vv.x; hb.y = (__bf16)vv.y;
            hb.z = (__bf16)vv.z; hb.w = (__bf16)vv.w;
            *(bf16x4*)(hb_base + (size_t)n * N_EDGES) = hb;
            *(bf16x4*)&tile[buf][r0 + 8 * k][equad * 4] = hb;
        }
        __syncthreads();
    }
    // transpose-out of last group (g=7, buf 1)
    {
        int pnb = 7 * 32;
#pragma unroll
        for (int s = 0; s < 2; ++s) {
            int id = s * 256 + t;
            int er = id >> 2, oct = id & 3;
            bf16x8 val;
#pragma unroll
            for (int j = 0; j < 8; ++j) val[j] = tile[1][oct * 8 + j][er];
            *(bf16x8*)(HbT + (size_t)(e0 + er) * N_NODES + n0 + pnb + oct * 8) = val;
        }
    }

    // logits reduce: intra-wave (r0 pairs) via shfl_xor(32)
#pragma unroll
    for (int ec = 0; ec < 4; ++ec)
#pragma unroll
        for (int qq = 0; qq < 4; ++qq)
#pragma unroll
            for (int qi = 0; qi < 4; ++qi)
                acc[ec][qq][qi] += __shfl_xor(acc[ec][qq][qi], 32, 64);

    __syncthreads();  // all tile/lav reads done before red overlay
    if (lane < 32) {
        // red[wv][q][el]: write f32x4 over ec at el = equad*4 -> conflict-free b128
#pragma unroll
        for (int qq = 0; qq < 4; ++qq)
#pragma unroll
            for (int qi = 0; qi < 4; ++qi) {
                f32x4 tmp = {acc[0][qq][qi], acc[1][qq][qi],
                             acc[2][qq][qi], acc[3][qq][qi]};
                *(f32x4*)&red[wv * 2048 + (qq * 4 + qi) * 128 + equad * 4] = tmp;
            }
    }
    __syncthreads();
#pragma unroll
    for (int s = 0; s < 8; ++s) {
        int id = s * 256 + t;  // 2048 = 16 q x 128 el
        int q = id >> 7, el = id & 127;
        float sum = red[q * 128 + el] + red[2048 + q * 128 + el] +
                    red[4096 + q * 128 + el] + red[6144 + q * 128 + el];
        plog[((size_t)blockIdx.y * 16 + q) * N_EDGES + e0 + el] = sum;
    }
}

// ---------- logits[q][e] = sum_nb plog[nb][q][e] ----------
__launch_bounds__(256)
__global__ void reduce_logits_kernel(const float* __restrict__ plog,
                                     float* __restrict__ logits) {
    int id = blockIdx.x * 256 + threadIdx.x;  // 65536 = 16 q x 4096 e
    int q = id >> 12, e = id & 4095;
    float s = 0.f;
#pragma unroll
    for (int nb = 0; nb < 32; ++nb)
        s += plog[((size_t)nb * 16 + q) * N_EDGES + e];
    logits[(size_t)q * N_EDGES + e] = s;
}

// ---------- W (fp32 F_INS x HDIM) -> WbT (bf16 HDIM x F_INS) ----------
__launch_bounds__(256)
__global__ void wbt_kernel(const float* __restrict__ W, __bf16* __restrict__ WbT) {
    int i = blockIdx.x * 256 + threadIdx.x;  // 512*256 = 131072
    int c = i >> 8, f = i & 255;
    WbT[i] = (__bf16)W[(size_t)f * HDIM + c];
}

// ---------- Wa[f][h] = sum_d W[f][h*64+d] * a[d]  (fp32, exact path for av) ----------
__launch_bounds__(256)
__global__ void wa_kernel(const float* __restrict__ W, const float* __restrict__ a,
                          float* __restrict__ Wa) {
    int i = blockIdx.x * 256 + threadIdx.x;  // 2048
    if (i >= F_INS * HEADS) return;
    int f = i >> 3, h = i & 7;
    float s = 0.f;
#pragma unroll 8
    for (int d = 0; d < DOUT; ++d) s += W[(size_t)f * HDIM + h * DOUT + d] * a[d];
    Wa[i] = s;
}

// ---------- fused: av = leaky_relu(x . Wa) fp32  +  xb = bf16(x) ----------
__launch_bounds__(256)
__global__ void av_kernel(const float* __restrict__ x, const float* __restrict__ Wa,
                          float* __restrict__ av, __bf16* __restrict__ xb) {
    __shared__ float lx[32][257];
    __shared__ float lwa[F_INS * HEADS];
    int t = threadIdx.x;
    size_t row0 = (size_t)blockIdx.x * 32;  // rows = b*8192+n, 16384 total
    for (int p = t; p < F_INS * HEADS; p += 256) lwa[p] = Wa[p];
#pragma unroll
    for (int p = 0; p < 32; ++p) {
        float v = x[(row0 + p) * F_INS + t];
        lx[p][t] = v;
        xb[(row0 + p) * F_INS + t] = (__bf16)v;
    }
    __syncthreads();
    int r = t >> 3, h = t & 7;
    float acc = 0.f;
#pragma unroll 8
    for (int f = 0; f < F_INS; ++f) acc += lx[r][f] * lwa[f * 8 + h];
    av[(row0 + r) * 8 + h] = acc > 0.f ? acc : 0.2f * acc;
}

// ---------- softmax over e for each of 16 (b,h) rows, in place ----------
__launch_bounds__(256)
__global__ void softmax_kernel(float* __restrict__ logits) {
    __shared__ float red[4];
    __shared__ float reds[4];
    int t = threadIdx.x;
    float* row = logits + (size_t)blockIdx.x * N_EDGES;
    float mx = -1e30f;
    for (int i = t; i < N_EDGES; i += 256) mx = fmaxf(mx, row[i]);
#pragma unroll
    for (int o = 32; o > 0; o >>= 1) mx = fmaxf(mx, __shfl_xor(mx, o, 64));
    if ((t & 63) == 0) red[t >> 6] = mx;
    __syncthreads();
    mx = fmaxf(fmaxf(red[0], red[1]), fmaxf(red[2], red[3]));
    float s = 0.f;
    for (int i = t; i < N_EDGES; i += 256) {
        float v = expf(row[i] - mx);
        row[i] = v;
        s += v;
    }
#pragma unroll
    for (int o = 32; o > 0; o >>= 1) s += __shfl_xor(s, o, 64);
    if ((t & 63) == 0) reds[t >> 6] = s;
    __syncthreads();
    float inv = 1.0f / (reds[0] + reds[1] + reds[2] + reds[3]);
    for (int i = t; i < N_EDGES; i += 256) row[i] *= inv;
}

// ---------- 128x128 bf16 MFMA GEMM (m97 structure) — used only for the small K=256
// WhbT GEMM. MODE 0: store bf16 to outB[gm*ldo+gc] (+out_z per z).
template <int MODE>
__launch_bounds__(256, 4)
__global__ void gemm_bt(const __bf16* __restrict__ A, const __bf16* __restrict__ BT,
                        int lda, int ldbt, int K,
                        size_t a_bz, size_t bt_bz, size_t out_z,
                        __bf16* __restrict__ outB, int ldo,
                        float* __restrict__ outF) {
    __shared__ __bf16 AsF[8192];
    __shared__ __bf16 BsF[8192];
    int t = threadIdx.x;
    int bz = blockIdx.z;
    A  += (size_t)bz * a_bz;
    BT += (size_t)bz * bt_bz;
    if (MODE == 0) outB += (size_t)bz * out_z;
    if (MODE == 1) outF += (size_t)bz * out_z;
    size_t m0 = (size_t)blockIdx.y * 128;
    size_t n0 = (size_t)blockIdx.x * 128;

    int lane = t & 63, wv = t >> 6;
    int ln = lane & 15, lk = lane >> 4;

    const __bf16* pA[4]; const __bf16* pB[4];
    __bf16* lA[4]; __bf16* lB[4];
#pragma unroll
    for (int p = 0; p < 4; ++p) {
        int bid = wv * 4 + p;
        int mb = bid >> 1, kb = bid & 1;
        pA[p] = A + (m0 + mb * 16 + ln) * (size_t)lda + kb * 32 + lk * 8;
        pB[p] = BT + (n0 + mb * 16 + ln) * (size_t)ldbt + kb * 32 + lk * 8;
        lA[p] = &AsF[bid * 512];
        lB[p] = &BsF[bid * 512];
    }

    int wm16 = (wv & 1) * 4, wn16 = (wv >> 1) * 4;
    f32x4 acc[4][4] = {};

    for (int k0 = 0; k0 < K; k0 += 64) {
        __syncthreads();
#pragma unroll
        for (int p = 0; p < 4; ++p) gld_lds16(pA[p] + k0, lA[p]);
#pragma unroll
        for (int p = 0; p < 4; ++p) gld_lds16(pB[p] + k0, lB[p]);
        __syncthreads();
#pragma unroll
        for (int ksb = 0; ksb < 2; ++ksb) {
            bf16x8 af[4], bfr[4];
#pragma unroll
            for (int i = 0; i < 4; ++i)
                af[i] = *(const bf16x8*)&AsF[((wm16 + i) * 2 + ksb) * 512 + lane * 8];
#pragma unroll
            for (int j = 0; j < 4; ++j)
                bfr[j] = *(const bf16x8*)&BsF[((wn16 + j) * 2 + ksb) * 512 + lane * 8];
#pragma unroll
            for (int i = 0; i < 4; ++i)
#pragma unroll
                for (int j = 0; j < 4; ++j)
                    acc[i][j] = __builtin_amdgcn_mfma_f32_16x16x32_bf16(
                        af[i], bfr[j], acc[i][j], 0, 0, 0);
        }
    }

    int wm = (wv & 1) * 64, wn = (wv >> 1) * 64;
#pragma unroll
    for (int i = 0; i < 4; ++i)
#pragma unroll
        for (int j = 0; j < 4; ++j)
#pragma unroll
            for (int rg = 0; rg < 4; ++rg) {
                int gm = (int)m0 + wm + i * 16 + lk * 4 + rg;
                int gc = (int)n0 + wn + j * 16 + ln;
                float v = acc[i][j][rg];
                if (MODE == 0) {
                    outB[(size_t)gm * ldo + gc] = (__bf16)v;
                } else if (MODE == 1) {
                    outF[(size_t)gm * ldo + gc] = v;
                } else {
                    outF[(size_t)(gc >> 9) * ((size_t)N_NODES * HDIM) +
                         (size_t)gm * HDIM + (gc & 511)] = v;
                }
            }
}

// ---------- 256x256 8-phase deep-pipelined bf16 GEMM (T3+T4+T5) ----------
// BK=64, 8 waves (512 thr, 2M x 4N), LDS = 2 buf x (A 32 frag + B 32 frag) x 1KB
// = 128 KB, fragment-major (conflict-free ds_read_b128, linear gld_lds dest).
// 4 phases per K-tile; each phase: {12 ds_read quadrant, stage 2 frags of tile
// t+1, s_waitcnt vmcnt(4), s_barrier, 16 MFMA in setprio(1)}. Stage pair for
// phase p is exactly the frag set FIRST consumed at phase p of the next tile:
// p0: A-mhalf0, p1: B-nhalf0, p2: B-nhalf1, p3: A-mhalf1 (min 3-phase slack,
// guaranteed landed by vmcnt(4) at the preceding phase). One barrier/phase is
// race-free: it sits after all ds_reads (lgkm-tracked by compiler before MFMA
// use) and all DMA stage-writes target the non-compute buffer.
// C[m][n] = sum_k A[m][k]*BT[n][k]; fp32 store outF[gm*ldo+gc] (+out_z per z).
// Requires K % 64 == 0, K >= 128.
template <int SWZ>
__launch_bounds__(512, 2)
__global__ void gemm256(const __bf16* __restrict__ A, const __bf16* __restrict__ BT,
                        int lda, int ldbt, int K,
                        size_t a_bz, size_t bt_bz, size_t out_z,
                        float* __restrict__ outF, int ldo) {
    __shared__ __bf16 lds[2 * 2 * 32 * 512];  // [buf][op][frag][512], 128 KB
#define LOFF(b, op, fr) ((((b) * 2 + (op)) * 32 + (fr)) * 512)
    int bx, by, bz;
    if (SWZ) {
        // bijective XCD remap for grid (4,32,2): A-panel-sharing bx quads land
        // on one XCD.
        int g = (int)blockIdx.x + 4 * ((int)blockIdx.y + 32 * (int)blockIdx.z);
        int xcd = g & 7, j = g >> 3;
        int l = (j & 3) + 4 * xcd + 32 * (j >> 2);
        bx = l & 3; by = (l >> 2) & 31; bz = l >> 7;
    } else {
        bx = blockIdx.x; by = blockIdx.y; bz = blockIdx.z;
    }
    A    += (size_t)bz * a_bz;
    BT   += (size_t)bz * bt_bz;
    outF += (size_t)bz * out_z;
    size_t m0 = (size_t)by * 256;
    size_t n0 = (size_t)bx * 256;

    int t = threadIdx.x;
    int lane = t & 63, wv = t >> 6;     // 8 waves
    int ln = lane & 15, lk = lane >> 4;
    int wmf = (wv >> 2) * 8;            // wave m-frag base (0 or 8)
    int wnf = (wv & 3) * 4;             // wave n-frag base (0,4,8,12)

    // staging assignment (per wave): one mb/nb per pair, both ks each
    int mbA0 = (wv < 4) ? wv : wv + 4;       // pair0: A-mhalf0 (mb 0-3, 8-11)
    int mbA1 = (wv < 4) ? wv + 4 : wv + 8;   // pair3: A-mhalf1 (mb 4-7, 12-15)
    int nbB0 = (wv >> 1) * 4 + (wv & 1);     // pair1: B-nhalf0 (nb 0,1,4,5,...)
    int nbB1 = nbB0 + 2;                     // pair2: B-nhalf1 (nb 2,3,6,7,...)
    const __bf16* gA0 = A + (m0 + mbA0 * 16 + ln) * (size_t)lda + lk * 8;
    const __bf16* gA1 = A + (m0 + mbA1 * 16 + ln) * (size_t)lda + lk * 8;
    const __bf16* gB0 = BT + (n0 + nbB0 * 16 + ln) * (size_t)ldbt + lk * 8;
    const __bf16* gB1 = BT + (n0 + nbB1 * 16 + ln) * (size_t)ldbt + lk * 8;

    int NT = K >> 6;  // K-tiles of 64

    // prologue: stage tile 0 (buf 0), pair order 0,1,2,3
    gld_lds16(gA0, &lds[LOFF(0, 0, mbA0 * 2 + 0)]);
    gld_lds16(gA0 + 32, &lds[LOFF(0, 0, mbA0 * 2 + 1)]);
    gld_lds16(gB0, &lds[LOFF(0, 1, nbB0 * 2 + 0)]);
    gld_lds16(gB0 + 32, &lds[LOFF(0, 1, nbB0 * 2 + 1)]);
    gld_lds16(gB1, &lds[LOFF(0, 1, nbB1 * 2 + 0)]);
    gld_lds16(gB1 + 32, &lds[LOFF(0, 1, nbB1 * 2 + 1)]);
    gld_lds16(gA1, &lds[LOFF(0, 0, mbA1 * 2 + 0)]);
    gld_lds16(gA1 + 32, &lds[LOFF(0, 0, mbA1 * 2 + 1)]);
    asm volatile("s_waitcnt vmcnt(4)" ::: "memory");  // pair0+pair1 landed
    __builtin_amdgcn_s_barrier();
    __builtin_amdgcn_sched_barrier(0);

    f32x4 acc[8][4] = {};

#define PHASE(TL, P, DO_STAGE, VMN)                                            \
    {                                                                          \
        const int c_ = (TL) & 1;                                               \
        bf16x8 af_[4][2], bf_[2][2];                                           \
        _Pragma("unroll") for (int mi = 0; mi < 4; ++mi)                       \
            _Pragma("unroll") for (int ks = 0; ks < 2; ++ks)                   \
                af_[mi][ks] = *(const bf16x8*)&lds[                            \
                    LOFF(c_, 0, (wmf + ((P) >> 1) * 4 + mi) * 2 + ks) + lane * 8]; \
        _Pragma("unroll") for (int nj = 0; nj < 2; ++nj)                       \
            _Pragma("unroll") for (int ks = 0; ks < 2; ++ks)                   \
                bf_[nj][ks] = *(const bf16x8*)&lds[                            \
                    LOFF(c_, 1, (wnf + ((P) & 1) * 2 + nj) * 2 + ks) + lane * 8]; \
        if (DO_STAGE) {                                                        \
            const int ub_ = ((TL) + 1) & 1;                                    \
            const int ko_ = ((TL) + 1) * 64;                                   \
            if ((P) == 0) {                                                    \
                gld_lds16(gA0 + ko_, &lds[LOFF(ub_, 0, mbA0 * 2 + 0)]);        \
                gld_lds16(gA0 + ko_ + 32, &lds[LOFF(ub_, 0, mbA0 * 2 + 1)]);   \
            } else if ((P) == 1) {                                             \
                gld_lds16(gB0 + ko_, &lds[LOFF(ub_, 1, nbB0 * 2 + 0)]);        \
                gld_lds16(gB0 + ko_ + 32, &lds[LOFF(ub_, 1, nbB0 * 2 + 1)]);   \
            } else if ((P) == 2) {                                             \
                gld_lds16(gB1 + ko_, &lds[LOFF(ub_, 1, nbB1 * 2 + 0)]);        \
                gld_lds16(gB1 + ko_ + 32, &lds[LOFF(ub_, 1, nbB1 * 2 + 1)]);   \
            } else {                                                           \
                gld_lds16(gA1 + ko_, &lds[LOFF(ub_, 0, mbA1 * 2 + 0)]);        \
                gld_lds16(gA1 + ko_ + 32, &lds[LOFF(ub_, 0, mbA1 * 2 + 1)]);   \
            }                                                                  \
        }                                                                      \
        if ((VMN) >= 0)                                                        \
            asm volatile("s_waitcnt vmcnt(%0)" ::"i"(VMN) : "memory");         \
        __builtin_amdgcn_s_barrier();                                          \
        __builtin_amdgcn_sched_barrier(0);                                     \
        __builtin_amdgcn_s_setprio(1);                                         \
        _Pragma("unroll") for (int mi = 0; mi < 4; ++mi)                       \
            _Pragma("unroll") for (int nj = 0; nj < 2; ++nj)                   \
                _Pragma("unroll") for (int ks = 0; ks < 2; ++ks)               \
                    acc[((P) >> 1) * 4 + mi][((P) & 1) * 2 + nj] =             \
                        __builtin_amdgcn_mfma_f32_16x16x32_bf16(               \
                            af_[mi][ks], bf_[nj][ks],                          \
                            acc[((P) >> 1) * 4 + mi][((P) & 1) * 2 + nj],      \
                            0, 0, 0);                                          \
        __builtin_amdgcn_s_setprio(0);                                         \
    }

    for (int tl = 0; tl < NT - 1; ++tl) {
        PHASE(tl, 0, 1, 4);
        PHASE(tl, 1, 1, 4);
        PHASE(tl, 2, 1, 4);
        PHASE(tl, 3, 1, 4);
    }
    // epilogue tile NT-1: no staging; drain 2 -> 0
    PHASE(NT - 1, 0, 0, 2);
    PHASE(NT - 1, 1, 0, 0);
    PHASE(NT - 1, 2, 0, -1);
    PHASE(NT - 1, 3, 0, -1);
#undef PHASE
#undef LOFF

    int wm = (wv >> 2) * 128, wn = (wv & 3) * 64;
#pragma unroll
    for (int i = 0; i < 8; ++i)
#pragma unroll
        for (int j = 0; j < 4; ++j)
#pragma unroll
            for (int rg = 0; rg < 4; ++rg) {
                int gm = (int)m0 + wm + i * 16 + lk * 4 + rg;
                int gc = (int)n0 + wn + j * 16 + ln;
                outF[(size_t)gm * ldo + gc] = acc[i][j][rg];
            }
}

// ---------- mwT = bf16( (slab0+slab1+slab2+slab3) * ae ) ----------
__launch_bounds__(256)
__global__ void scale1_kernel(const float* __restrict__ acc1, const float* __restrict__ ae,
                              __bf16* __restrict__ mwT) {
    int i = blockIdx.x * 256 + threadIdx.x;  // float4 index, 1M total
    size_t base = (size_t)i * 4;
    int c = (int)(base >> 12);
    int e = (int)(base & 4095);
    const size_t slab = (size_t)CCOMB * N_EDGES / 4;  // float4 units
    float4 s0 = ((const float4*)acc1)[i];
    float4 s1 = ((const float4*)acc1)[i + slab];
    float4 s2 = ((const float4*)acc1)[i + 2 * slab];
    float4 s3 = ((const float4*)acc1)[i + 3 * slab];
    float4 a4 = *(const float4*)(ae + ((size_t)(c >> 6) << 12) + e);
    bf16x4 o;
    o.x = (__bf16)((s0.x + s1.x + s2.x + s3.x) * a4.x);
    o.y = (__bf16)((s0.y + s1.y + s2.y + s3.y) * a4.y);
    o.z = (__bf16)((s0.z + s1.z + s2.z + s3.z) * a4.z);
    o.w = (__bf16)((s0.w + s1.w + s2.w + s3.w) * a4.w);
    ((bf16x4*)mwT)[i] = o;
}

// ---------- out[b][n][hd] = slab0[n][c] + slab1[n][c],  c = b*512+hd ----------
__launch_bounds__(256)
__global__ void reduce2_kernel(const float* __restrict__ s, float* __restrict__ out) {
    int i = blockIdx.x * 256 + threadIdx.x;      // float4 units: 8192*1024/4
    size_t base = (size_t)i * 4;
    int m = (int)(base >> 10);
    int c = (int)(base & 1023);
    const size_t slab = (size_t)N_NODES * CCOMB / 4;  // float4 units
    float4 a = ((const float4*)s)[i];
    float4 b = ((const float4*)s)[i + slab];
    float4 o;
    o.x = a.x + b.x; o.y = a.y + b.y; o.z = a.z + b.z; o.w = a.w + b.w;
    *(float4*)&out[(size_t)(c >> 9) * ((size_t)N_NODES * HDIM) +
                   (size_t)m * HDIM + (c & 511)] = o;
}

extern "C" void kernel_launch(void* const* d_in, const int* in_sizes, int n_in,
                              void* d_out, int out_size, void* d_ws, size_t ws_size,
                              hipStream_t stream) {
    const float* x = (const float*)d_in[0];
    const float* H = (const float*)d_in[1];
    const float* W = (const float*)d_in[2];
    const float* a = (const float*)d_in[3];
    float* out = (float*)d_out;

    // workspace carve-up (~235 MB)
    char* p = (char*)d_ws;
    __bf16* Hb   = (__bf16*)p; p += (size_t)N_NODES * N_EDGES * 2;   // 67.1 MB
    __bf16* HbT  = (__bf16*)p; p += (size_t)N_EDGES * N_NODES * 2;   // 67.1 MB
    __bf16* xb   = (__bf16*)p; p += (size_t)BATCH * N_NODES * F_INS * 2; // 8.4 MB
    __bf16* WbT  = (__bf16*)p; p += (size_t)HDIM * F_INS * 2;        // 0.26 MB
    __bf16* WhbT = (__bf16*)p; p += (size_t)CCOMB * N_NODES * 2;     // 16.8 MB
    __bf16* mwT  = (__bf16*)p; p += (size_t)CCOMB * N_EDGES * 2;     // 8.4 MB
    float*  Wa   = (float*)p;  p += (size_t)F_INS * HEADS * 4;
    float*  av   = (float*)p;  p += (size_t)BATCH * N_NODES * HEADS * 4;
    float*  ae   = (float*)p;  p += (size_t)16 * N_EDGES * 4;        // logits->softmax in place
    float*  acc1 = (float*)p;  p += (size_t)4 * CCOMB * N_EDGES * 4; // 67.1 MB: 4 fp32 slabs
    // plog (32 nb x 16 q x 4096 e fp32 = 8 MB) overlays acc1: its lifetime
    // (convert_H -> reduce_logits) ends before gemm256<0> first writes acc1.
    float*  plog = acc1;

    wbt_kernel<<<dim3(HDIM * F_INS / 256), 256, 0, stream>>>(W, WbT);
    wa_kernel<<<dim3(8), 256, 0, stream>>>(W, a, Wa);
    av_kernel<<<dim3(BATCH * N_NODES / 32), 256, 0, stream>>>(x, Wa, av, xb);
    convert_H_logits_kernel<<<dim3(N_EDGES / 128, N_NODES / 256), 256, 0, stream>>>(
        H, av, Hb, HbT, plog);
    reduce_logits_kernel<<<dim3(256), 256, 0, stream>>>(plog, ae);
    softmax_kernel<<<dim3(16), 256, 0, stream>>>(ae);

    // WhbT[b*512+c][n] = sum_f WbT[c][f] * xb[b][n][f]   (K=256, m97 structure is fine)
    gemm_bt<0><<<dim3(64, 4, 2), 256, 0, stream>>>(
        WbT, xb, F_INS, F_INS, F_INS,
        0, (size_t)N_NODES * F_INS, (size_t)HDIM * N_NODES,
        WhbT, N_NODES, nullptr);

    // acc1 slab z: [c][e] = sum over n-slab of WhbT[c][n]*HbT[e][n]
    // 8-phase 256x256; K=8192 -> 4 slabs of 2048; 16*4*4 = 256 blocks = 1/CU
    gemm256<0><<<dim3(16, 4, 4), 512, 0, stream>>>(
        WhbT, HbT, N_NODES, N_NODES, 2048,
        2048, 2048, (size_t)CCOMB * N_EDGES,
        acc1, N_EDGES);

    // mwT[c][e] = bf16( (sum of 4 slabs) * ae[c>>6][e] )
    scale1_kernel<<<dim3(CCOMB * N_EDGES / 4 / 256), 256, 0, stream>>>(acc1, ae, mwT);

    // out-slab z (into acc1, now free): [n][c] = sum over e-slab of Hb[n][e]*mwT[c][e]
    // K=4096 -> 2 slabs of 2048; 4*32*2 = 256 blocks = 1/CU; XCD swizzle for A-panel reuse
    gemm256<1><<<dim3(4, 32, 2), 512, 0, stream>>>(
        Hb, mwT, N_EDGES, N_EDGES, 2048,
        2048, 2048, (size_t)N_NODES * CCOMB,
        acc1, CCOMB);

    // out[b][n][hd] = slab0 + slab1 (scatter to final layout)
    reduce2_kernel<<<dim3(N_NODES * CCOMB / 4 / 256), 256, 0, stream>>>(acc1, out);
}

// Round 7
// 474.718 us; speedup vs baseline: 1.4854x; 1.0027x over previous
//
#include <hip/hip_runtime.h>

#define N_NODES 8192
#define N_EDGES 4096
#define F_INS   256
#define HEADS   8
#define DOUT    64
#define HDIM    512   // HEADS*DOUT
#define CCOMB   1024  // 2*HDIM (both batches as columns)
#define BATCH   2

typedef __bf16 bf16x8 __attribute__((ext_vector_type(8)));
typedef __bf16 bf16x4 __attribute__((ext_vector_type(4)));
typedef float  f32x4  __attribute__((ext_vector_type(4)));

// async 16B global->LDS (wave-uniform LDS base + lane*16)
__device__ __forceinline__ void gld_lds16(const __bf16* g, __bf16* l) {
    __builtin_amdgcn_global_load_lds(
        (const __attribute__((address_space(1))) void*)g,
        (__attribute__((address_space(3))) void*)l, 16, 0, 0);
}

// ---------- fused: H fp32 -> Hb/HbT bf16  +  plog partials (fp32 exact, atomic-free) ----
// v4: gld_lds-staged fp32 H tiles (async DMA, no VGPR prefetch buffers -> no
// spill), 2 x 16KB LDS double buffer, stage ONE group ahead, counted vmcnt +
// raw s_barrier. HbT transposed directly from the fp32 tile (bf16 tile gone).
// vmcnt ledger (stores count in vmcnt; 6 stores/thread/group = 4 Hb + 2 HbT):
//   prologue: [lav(16), D0(4), D1(4)] -> vmcnt(4) leaves D1, D0 landed.
//   end of iter g (after staging D_{g+2}): [D_{g+1}(4), S_g(6), D_{g+2}(4)]
//     -> vmcnt(10) drains D_{g+1} (needed by iter g+1). g==6 (no stage):
//     [D_7(4), S_6(6)] -> vmcnt(6).
__launch_bounds__(256, 3)
__global__ void convert_H_logits_kernel(const float* __restrict__ H,
                                        const float* __restrict__ av,
                                        __bf16* __restrict__ Hb,
                                        __bf16* __restrict__ HbT,
                                        float* __restrict__ plog) {
    __shared__ __align__(16) float smem[12288];  // 48 KB
    float* lav  = smem;          // [256][16] = 16 KB
    float* hbuf = smem + 4096;   // [2][32][128] fp32 = 32 KB
    float* red  = hbuf;          // [4][16][128] overlay after pipeline ends

    int t = threadIdx.x;
    int e0 = blockIdx.x * 128;
    int n0 = blockIdx.y * 256;
    int lane = t & 63, wv = t >> 6;
    int equad = t & 31, r0 = t >> 5;

    // lav[n][q]: q = b*8+h (global loads drain in prologue vmcnt)
    for (int p = t; p < 4096; p += 256) {
        int n = p >> 4, q = p & 15, b = q >> 3, h = q & 7;
        lav[p] = av[(size_t)b * (N_NODES * 8) + (size_t)(n0 + n) * 8 + h];
    }

    // stage geometry: call c moves rows [8*wv+2c, +2) of the 32-row group;
    // lane l supplies 16B at row +(l>>5), cols (l&31)*4; LDS dest linear.
    const float* gsrc = H + (size_t)(n0 + 8 * wv + (lane >> 5)) * N_EDGES
                          + e0 + (lane & 31) * 4;

#define STAGE_H(GG, BUF)                                                        \
    {                                                                           \
        _Pragma("unroll")                                                       \
        for (int c = 0; c < 4; ++c)                                             \
            gld_lds16((const __bf16*)(gsrc + ((size_t)(GG) * 32 + 2 * c) * N_EDGES), \
                      (__bf16*)(hbuf + (BUF) * 4096 + (8 * wv + 2 * c) * 128)); \
    }

    STAGE_H(0, 0);
    STAGE_H(1, 1);
    asm volatile("s_waitcnt vmcnt(4) lgkmcnt(0)" ::: "memory");  // D0 + lav done
    __builtin_amdgcn_s_barrier();
    __builtin_amdgcn_sched_barrier(0);

    f32x4 acc[4][4] = {};  // [ec][qq], components = qi

    for (int g = 0; g < 8; ++g) {
        int cb = g & 1;
        const float* hb = hbuf + cb * 4096;
        // compute: FMA into acc + Hb bf16 store (4 stores)
#pragma unroll
        for (int k = 0; k < 4; ++k) {
            int r = r0 + 8 * k;
            int n = g * 32 + r;
            f32x4 vv = *(const f32x4*)(hb + r * 128 + equad * 4);
            const f32x4* lrow = (const f32x4*)&lav[n * 16];
#pragma unroll
            for (int qq = 0; qq < 4; ++qq) {
                f32x4 l = lrow[qq];
                acc[0][qq] += l * vv[0];
                acc[1][qq] += l * vv[1];
                acc[2][qq] += l * vv[2];
                acc[3][qq] += l * vv[3];
            }
            bf16x4 hbv;
            hbv[0] = (__bf16)vv[0]; hbv[1] = (__bf16)vv[1];
            hbv[2] = (__bf16)vv[2]; hbv[3] = (__bf16)vv[3];
            *(bf16x4*)(Hb + (size_t)(n0 + n) * N_EDGES + e0 + equad * 4) = hbv;
        }
        // transpose out of fp32 tile -> HbT (2 stores; 2-way LDS alias = free)
        {
            int er = t >> 1, half = t & 1;
            const float* colp = hb + half * 16 * 128 + er;
            bf16x8 v0, v1;
#pragma unroll
            for (int j = 0; j < 8; ++j) v0[j] = (__bf16)colp[j * 128];
#pragma unroll
            for (int j = 0; j < 8; ++j) v1[j] = (__bf16)colp[(8 + j) * 128];
            __bf16* dst = HbT + (size_t)(e0 + er) * N_NODES + n0 + g * 32 + half * 16;
            *(bf16x8*)dst = v0;
            *(bf16x8*)(dst + 8) = v1;
        }
        // all this wave's LDS reads sampled before anyone overwrites cb
        asm volatile("s_waitcnt lgkmcnt(0)" ::: "memory");
        __builtin_amdgcn_s_barrier();
        __builtin_amdgcn_sched_barrier(0);
        if (g < 6) STAGE_H(g + 2, cb);
        if (g < 7) {
            if (g == 6)
                asm volatile("s_waitcnt vmcnt(6)" ::: "memory");
            else
                asm volatile("s_waitcnt vmcnt(10)" ::: "memory");
            __builtin_amdgcn_s_barrier();
            __builtin_amdgcn_sched_barrier(0);
        }
    }
#undef STAGE_H

    // logits reduce: intra-wave (r0 pairs) via shfl_xor(32)
#pragma unroll
    for (int ec = 0; ec < 4; ++ec)
#pragma unroll
        for (int qq = 0; qq < 4; ++qq)
#pragma unroll
            for (int qi = 0; qi < 4; ++qi)
                acc[ec][qq][qi] += __shfl_xor(acc[ec][qq][qi], 32, 64);

    // hbuf free (all waves passed the iter-7 barrier); write red overlay
    if (lane < 32) {
        // red[wv][q][el]: f32x4 over ec at el = equad*4 -> conflict-free b128
#pragma unroll
        for (int qq = 0; qq < 4; ++qq)
#pragma unroll
            for (int qi = 0; qi < 4; ++qi) {
                f32x4 tmp = {acc[0][qq][qi], acc[1][qq][qi],
                             acc[2][qq][qi], acc[3][qq][qi]};
                *(f32x4*)&red[wv * 2048 + (qq * 4 + qi) * 128 + equad * 4] = tmp;
            }
    }
    __syncthreads();
#pragma unroll
    for (int s = 0; s < 8; ++s) {
        int id = s * 256 + t;  // 2048 = 16 q x 128 el
        int q = id >> 7, el = id & 127;
        float sum = red[q * 128 + el] + red[2048 + q * 128 + el] +
                    red[4096 + q * 128 + el] + red[6144 + q * 128 + el];
        plog[((size_t)blockIdx.y * 16 + q) * N_EDGES + e0 + el] = sum;
    }
}

// ---------- logits[q][e] = sum_nb plog[nb][q][e] ----------
__launch_bounds__(256)
__global__ void reduce_logits_kernel(const float* __restrict__ plog,
                                     float* __restrict__ logits) {
    int id = blockIdx.x * 256 + threadIdx.x;  // 65536 = 16 q x 4096 e
    int q = id >> 12, e = id & 4095;
    float s = 0.f;
#pragma unroll
    for (int nb = 0; nb < 32; ++nb)
        s += plog[((size_t)nb * 16 + q) * N_EDGES + e];
    logits[(size_t)q * N_EDGES + e] = s;
}

// ---------- W (fp32 F_INS x HDIM) -> WbT (bf16 HDIM x F_INS) ----------
__launch_bounds__(256)
__global__ void wbt_kernel(const float* __restrict__ W, __bf16* __restrict__ WbT) {
    int i = blockIdx.x * 256 + threadIdx.x;  // 512*256 = 131072
    int c = i >> 8, f = i & 255;
    WbT[i] = (__bf16)W[(size_t)f * HDIM + c];
}

// ---------- Wa[f][h] = sum_d W[f][h*64+d] * a[d]  (fp32, exact path for av) ----------
__launch_bounds__(256)
__global__ void wa_kernel(const float* __restrict__ W, const float* __restrict__ a,
                          float* __restrict__ Wa) {
    int i = blockIdx.x * 256 + threadIdx.x;  // 2048
    if (i >= F_INS * HEADS) return;
    int f = i >> 3, h = i & 7;
    float s = 0.f;
#pragma unroll 8
    for (int d = 0; d < DOUT; ++d) s += W[(size_t)f * HDIM + h * DOUT + d] * a[d];
    Wa[i] = s;
}

// ---------- fused: av = leaky_relu(x . Wa) fp32  +  xb = bf16(x) ----------
__launch_bounds__(256)
__global__ void av_kernel(const float* __restrict__ x, const float* __restrict__ Wa,
                          float* __restrict__ av, __bf16* __restrict__ xb) {
    __shared__ float lx[32][257];
    __shared__ float lwa[F_INS * HEADS];
    int t = threadIdx.x;
    size_t row0 = (size_t)blockIdx.x * 32;  // rows = b*8192+n, 16384 total
    for (int p = t; p < F_INS * HEADS; p += 256) lwa[p] = Wa[p];
#pragma unroll
    for (int p = 0; p < 32; ++p) {
        float v = x[(row0 + p) * F_INS + t];
        lx[p][t] = v;
        xb[(row0 + p) * F_INS + t] = (__bf16)v;
    }
    __syncthreads();
    int r = t >> 3, h = t & 7;
    float acc = 0.f;
#pragma unroll 8
    for (int f = 0; f < F_INS; ++f) acc += lx[r][f] * lwa[f * 8 + h];
    av[(row0 + r) * 8 + h] = acc > 0.f ? acc : 0.2f * acc;
}

// ---------- softmax over e for each of 16 (b,h) rows, in place ----------
__launch_bounds__(256)
__global__ void softmax_kernel(float* __restrict__ logits) {
    __shared__ float red[4];
    __shared__ float reds[4];
    int t = threadIdx.x;
    float* row = logits + (size_t)blockIdx.x * N_EDGES;
    float mx = -1e30f;
    for (int i = t; i < N_EDGES; i += 256) mx = fmaxf(mx, row[i]);
#pragma unroll
    for (int o = 32; o > 0; o >>= 1) mx = fmaxf(mx, __shfl_xor(mx, o, 64));
    if ((t & 63) == 0) red[t >> 6] = mx;
    __syncthreads();
    mx = fmaxf(fmaxf(red[0], red[1]), fmaxf(red[2], red[3]));
    float s = 0.f;
    for (int i = t; i < N_EDGES; i += 256) {
        float v = expf(row[i] - mx);
        row[i] = v;
        s += v;
    }
#pragma unroll
    for (int o = 32; o > 0; o >>= 1) s += __shfl_xor(s, o, 64);
    if ((t & 63) == 0) reds[t >> 6] = s;
    __syncthreads();
    float inv = 1.0f / (reds[0] + reds[1] + reds[2] + reds[3]);
    for (int i = t; i < N_EDGES; i += 256) row[i] *= inv;
}

// ---------- 128x128 bf16 MFMA GEMM (m97 structure) — used only for the small K=256
// WhbT GEMM. MODE 0: store bf16 to outB[gm*ldo+gc] (+out_z per z).
template <int MODE>
__launch_bounds__(256, 4)
__global__ void gemm_bt(const __bf16* __restrict__ A, const __bf16* __restrict__ BT,
                        int lda, int ldbt, int K,
                        size_t a_bz, size_t bt_bz, size_t out_z,
                        __bf16* __restrict__ outB, int ldo,
                        float* __restrict__ outF) {
    __shared__ __bf16 AsF[8192];
    __shared__ __bf16 BsF[8192];
    int t = threadIdx.x;
    int bz = blockIdx.z;
    A  += (size_t)bz * a_bz;
    BT += (size_t)bz * bt_bz;
    if (MODE == 0) outB += (size_t)bz * out_z;
    if (MODE == 1) outF += (size_t)bz * out_z;
    size_t m0 = (size_t)blockIdx.y * 128;
    size_t n0 = (size_t)blockIdx.x * 128;

    int lane = t & 63, wv = t >> 6;
    int ln = lane & 15, lk = lane >> 4;

    const __bf16* pA[4]; const __bf16* pB[4];
    __bf16* lA[4]; __bf16* lB[4];
#pragma unroll
    for (int p = 0; p < 4; ++p) {
        int bid = wv * 4 + p;
        int mb = bid >> 1, kb = bid & 1;
        pA[p] = A + (m0 + mb * 16 + ln) * (size_t)lda + kb * 32 + lk * 8;
        pB[p] = BT + (n0 + mb * 16 + ln) * (size_t)ldbt + kb * 32 + lk * 8;
        lA[p] = &AsF[bid * 512];
        lB[p] = &BsF[bid * 512];
    }

    int wm16 = (wv & 1) * 4, wn16 = (wv >> 1) * 4;
    f32x4 acc[4][4] = {};

    for (int k0 = 0; k0 < K; k0 += 64) {
        __syncthreads();
#pragma unroll
        for (int p = 0; p < 4; ++p) gld_lds16(pA[p] + k0, lA[p]);
#pragma unroll
        for (int p = 0; p < 4; ++p) gld_lds16(pB[p] + k0, lB[p]);
        __syncthreads();
#pragma unroll
        for (int ksb = 0; ksb < 2; ++ksb) {
            bf16x8 af[4], bfr[4];
#pragma unroll
            for (int i = 0; i < 4; ++i)
                af[i] = *(const bf16x8*)&AsF[((wm16 + i) * 2 + ksb) * 512 + lane * 8];
#pragma unroll
            for (int j = 0; j < 4; ++j)
                bfr[j] = *(const bf16x8*)&BsF[((wn16 + j) * 2 + ksb) * 512 + lane * 8];
#pragma unroll
            for (int i = 0; i < 4; ++i)
#pragma unroll
                for (int j = 0; j < 4; ++j)
                    acc[i][j] = __builtin_amdgcn_mfma_f32_16x16x32_bf16(
                        af[i], bfr[j], acc[i][j], 0, 0, 0);
        }
    }

    int wm = (wv & 1) * 64, wn = (wv >> 1) * 64;
#pragma unroll
    for (int i = 0; i < 4; ++i)
#pragma unroll
        for (int j = 0; j < 4; ++j)
#pragma unroll
            for (int rg = 0; rg < 4; ++rg) {
                int gm = (int)m0 + wm + i * 16 + lk * 4 + rg;
                int gc = (int)n0 + wn + j * 16 + ln;
                float v = acc[i][j][rg];
                if (MODE == 0) {
                    outB[(size_t)gm * ldo + gc] = (__bf16)v;
                } else if (MODE == 1) {
                    outF[(size_t)gm * ldo + gc] = v;
                } else {
                    outF[(size_t)(gc >> 9) * ((size_t)N_NODES * HDIM) +
                         (size_t)gm * HDIM + (gc & 511)] = v;
                }
            }
}

// ---------- 256x256 8-phase deep-pipelined bf16 GEMM (T3+T4+T5) ----------
// BK=64, 8 waves, 2x64KB LDS double buffer, fragment-major. 4 phases/K-tile:
// {12 ds_read quadrant, stage 2 frags of tile t+1, vmcnt(4), s_barrier,
// 16 MFMA in setprio}. See round-4 notes for the stage-pair/vmcnt proof.
// SWZ=1: XCD remap for grid (4,32,2). SWZ=2: XCD remap for grid (16,4,4) —
// each XCD owns 2 (by,bz) A-panels (same bz) x all 16 bx: A dedups in-XCD,
// concurrent by-pairs dedup B panels in L2.
template <int SWZ>
__launch_bounds__(512, 2)
__global__ void gemm256(const __bf16* __restrict__ A, const __bf16* __restrict__ BT,
                        int lda, int ldbt, int K,
                        size_t a_bz, size_t bt_bz, size_t out_z,
                        float* __restrict__ outF, int ldo) {
    __shared__ __bf16 lds[2 * 2 * 32 * 512];  // [buf][op][frag][512], 128 KB
#define LOFF(b, op, fr) ((((b) * 2 + (op)) * 32 + (fr)) * 512)
    int bx, by, bz;
    if (SWZ == 1) {
        int g = (int)blockIdx.x + 4 * ((int)blockIdx.y + 32 * (int)blockIdx.z);
        int xcd = g & 7, j = g >> 3;
        int l = (j & 3) + 4 * xcd + 32 * (j >> 2);
        bx = l & 3; by = (l >> 2) & 31; bz = l >> 7;
    } else if (SWZ == 2) {
        int g = (int)blockIdx.x + 16 * ((int)blockIdx.y + 4 * (int)blockIdx.z);
        int xcd = g & 7, j = g >> 3;        // j in [0,32)
        int pan = xcd * 2 + (j >> 4);       // panel = bz*4+by
        bx = j & 15; by = pan & 3; bz = pan >> 2;
    } else {
        bx = blockIdx.x; by = blockIdx.y; bz = blockIdx.z;
    }
    A    += (size_t)bz * a_bz;
    BT   += (size_t)bz * bt_bz;
    outF += (size_t)bz * out_z;
    size_t m0 = (size_t)by * 256;
    size_t n0 = (size_t)bx * 256;

    int t = threadIdx.x;
    int lane = t & 63, wv = t >> 6;     // 8 waves
    int ln = lane & 15, lk = lane >> 4;
    int wmf = (wv >> 2) * 8;            // wave m-frag base (0 or 8)
    int wnf = (wv & 3) * 4;             // wave n-frag base (0,4,8,12)

    // staging assignment (per wave): one mb/nb per pair, both ks each
    int mbA0 = (wv < 4) ? wv : wv + 4;       // pair0: A-mhalf0 (mb 0-3, 8-11)
    int mbA1 = (wv < 4) ? wv + 4 : wv + 8;   // pair3: A-mhalf1 (mb 4-7, 12-15)
    int nbB0 = (wv >> 1) * 4 + (wv & 1);     // pair1: B-nhalf0 (nb 0,1,4,5,...)
    int nbB1 = nbB0 + 2;                     // pair2: B-nhalf1 (nb 2,3,6,7,...)
    const __bf16* gA0 = A + (m0 + mbA0 * 16 + ln) * (size_t)lda + lk * 8;
    const __bf16* gA1 = A + (m0 + mbA1 * 16 + ln) * (size_t)lda + lk * 8;
    const __bf16* gB0 = BT + (n0 + nbB0 * 16 + ln) * (size_t)ldbt + lk * 8;
    const __bf16* gB1 = BT + (n0 + nbB1 * 16 + ln) * (size_t)ldbt + lk * 8;

    int NT = K >> 6;  // K-tiles of 64

    // prologue: stage tile 0 (buf 0), pair order 0,1,2,3
    gld_lds16(gA0, &lds[LOFF(0, 0, mbA0 * 2 + 0)]);
    gld_lds16(gA0 + 32, &lds[LOFF(0, 0, mbA0 * 2 + 1)]);
    gld_lds16(gB0, &lds[LOFF(0, 1, nbB0 * 2 + 0)]);
    gld_lds16(gB0 + 32, &lds[LOFF(0, 1, nbB0 * 2 + 1)]);
    gld_lds16(gB1, &lds[LOFF(0, 1, nbB1 * 2 + 0)]);
    gld_lds16(gB1 + 32, &lds[LOFF(0, 1, nbB1 * 2 + 1)]);
    gld_lds16(gA1, &lds[LOFF(0, 0, mbA1 * 2 + 0)]);
    gld_lds16(gA1 + 32, &lds[LOFF(0, 0, mbA1 * 2 + 1)]);
    asm volatile("s_waitcnt vmcnt(4)" ::: "memory");  // pair0+pair1 landed
    __builtin_amdgcn_s_barrier();
    __builtin_amdgcn_sched_barrier(0);

    f32x4 acc[8][4] = {};

#define PHASE(TL, P, DO_STAGE, VMN)                                            \
    {                                                                          \
        const int c_ = (TL) & 1;                                               \
        bf16x8 af_[4][2], bf_[2][2];                                           \
        _Pragma("unroll") for (int mi = 0; mi < 4; ++mi)                       \
            _Pragma("unroll") for (int ks = 0; ks < 2; ++ks)                   \
                af_[mi][ks] = *(const bf16x8*)&lds[                            \
                    LOFF(c_, 0, (wmf + ((P) >> 1) * 4 + mi) * 2 + ks) + lane * 8]; \
        _Pragma("unroll") for (int nj = 0; nj < 2; ++nj)                       \
            _Pragma("unroll") for (int ks = 0; ks < 2; ++ks)                   \
                bf_[nj][ks] = *(const bf16x8*)&lds[                            \
                    LOFF(c_, 1, (wnf + ((P) & 1) * 2 + nj) * 2 + ks) + lane * 8]; \
        if (DO_STAGE) {                                                        \
            const int ub_ = ((TL) + 1) & 1;                                    \
            const int ko_ = ((TL) + 1) * 64;                                   \
            if ((P) == 0) {                                                    \
                gld_lds16(gA0 + ko_, &lds[LOFF(ub_, 0, mbA0 * 2 + 0)]);        \
                gld_lds16(gA0 + ko_ + 32, &lds[LOFF(ub_, 0, mbA0 * 2 + 1)]);   \
            } else if ((P) == 1) {                                             \
                gld_lds16(gB0 + ko_, &lds[LOFF(ub_, 1, nbB0 * 2 + 0)]);        \
                gld_lds16(gB0 + ko_ + 32, &lds[LOFF(ub_, 1, nbB0 * 2 + 1)]);   \
            } else if ((P) == 2) {                                             \
                gld_lds16(gB1 + ko_, &lds[LOFF(ub_, 1, nbB1 * 2 + 0)]);        \
                gld_lds16(gB1 + ko_ + 32, &lds[LOFF(ub_, 1, nbB1 * 2 + 1)]);   \
            } else {                                                           \
                gld_lds16(gA1 + ko_, &lds[LOFF(ub_, 0, mbA1 * 2 + 0)]);        \
                gld_lds16(gA1 + ko_ + 32, &lds[LOFF(ub_, 0, mbA1 * 2 + 1)]);   \
            }                                                                  \
        }                                                                      \
        if ((VMN) >= 0)                                                        \
            asm volatile("s_waitcnt vmcnt(%0)" ::"i"(VMN) : "memory");         \
        __builtin_amdgcn_s_barrier();                                          \
        __builtin_amdgcn_sched_barrier(0);                                     \
        __builtin_amdgcn_s_setprio(1);                                         \
        _Pragma("unroll") for (int mi = 0; mi < 4; ++mi)                       \
            _Pragma("unroll") for (int nj = 0; nj < 2; ++nj)                   \
                _Pragma("unroll") for (int ks = 0; ks < 2; ++ks)               \
                    acc[((P) >> 1) * 4 + mi][((P) & 1) * 2 + nj] =             \
                        __builtin_amdgcn_mfma_f32_16x16x32_bf16(               \
                            af_[mi][ks], bf_[nj][ks],                          \
                            acc[((P) >> 1) * 4 + mi][((P) & 1) * 2 + nj],      \
                            0, 0, 0);                                          \
        __builtin_amdgcn_s_setprio(0);                                         \
    }

    for (int tl = 0; tl < NT - 1; ++tl) {
        PHASE(tl, 0, 1, 4);
        PHASE(tl, 1, 1, 4);
        PHASE(tl, 2, 1, 4);
        PHASE(tl, 3, 1, 4);
    }
    // epilogue tile NT-1: no staging; drain 2 -> 0
    PHASE(NT - 1, 0, 0, 2);
    PHASE(NT - 1, 1, 0, 0);
    PHASE(NT - 1, 2, 0, -1);
    PHASE(NT - 1, 3, 0, -1);
#undef PHASE
#undef LOFF

    int wm = (wv >> 2) * 128, wn = (wv & 3) * 64;
#pragma unroll
    for (int i = 0; i < 8; ++i)
#pragma unroll
        for (int j = 0; j < 4; ++j)
#pragma unroll
            for (int rg = 0; rg < 4; ++rg) {
                int gm = (int)m0 + wm + i * 16 + lk * 4 + rg;
                int gc = (int)n0 + wn + j * 16 + ln;
                outF[(size_t)gm * ldo + gc] = acc[i][j][rg];
            }
}

// ---------- mwT = bf16( (slab0+slab1+slab2+slab3) * ae ) ----------
__launch_bounds__(256)
__global__ void scale1_kernel(const float* __restrict__ acc1, const float* __restrict__ ae,
                              __bf16* __restrict__ mwT) {
    int i = blockIdx.x * 256 + threadIdx.x;  // float4 index, 1M total
    size_t base = (size_t)i * 4;
    int c = (int)(base >> 12);
    int e = (int)(base & 4095);
    const size_t slab = (size_t)CCOMB * N_EDGES / 4;  // float4 units
    float4 s0 = ((const float4*)acc1)[i];
    float4 s1 = ((const float4*)acc1)[i + slab];
    float4 s2 = ((const float4*)acc1)[i + 2 * slab];
    float4 s3 = ((const float4*)acc1)[i + 3 * slab];
    float4 a4 = *(const float4*)(ae + ((size_t)(c >> 6) << 12) + e);
    bf16x4 o;
    o.x = (__bf16)((s0.x + s1.x + s2.x + s3.x) * a4.x);
    o.y = (__bf16)((s0.y + s1.y + s2.y + s3.y) * a4.y);
    o.z = (__bf16)((s0.z + s1.z + s2.z + s3.z) * a4.z);
    o.w = (__bf16)((s0.w + s1.w + s2.w + s3.w) * a4.w);
    ((bf16x4*)mwT)[i] = o;
}

// ---------- out[b][n][hd] = slab0[n][c] + slab1[n][c],  c = b*512+hd ----------
__launch_bounds__(256)
__global__ void reduce2_kernel(const float* __restrict__ s, float* __restrict__ out) {
    int i = blockIdx.x * 256 + threadIdx.x;      // float4 units: 8192*1024/4
    size_t base = (size_t)i * 4;
    int m = (int)(base >> 10);
    int c = (int)(base & 1023);
    const size_t slab = (size_t)N_NODES * CCOMB / 4;  // float4 units
    float4 a = ((const float4*)s)[i];
    float4 b = ((const float4*)s)[i + slab];
    float4 o;
    o.x = a.x + b.x; o.y = a.y + b.y; o.z = a.z + b.z; o.w = a.w + b.w;
    *(float4*)&out[(size_t)(c >> 9) * ((size_t)N_NODES * HDIM) +
                   (size_t)m * HDIM + (c & 511)] = o;
}

extern "C" void kernel_launch(void* const* d_in, const int* in_sizes, int n_in,
                              void* d_out, int out_size, void* d_ws, size_t ws_size,
                              hipStream_t stream) {
    const float* x = (const float*)d_in[0];
    const float* H = (const float*)d_in[1];
    const float* W = (const float*)d_in[2];
    const float* a = (const float*)d_in[3];
    float* out = (float*)d_out;

    // workspace carve-up (~235 MB)
    char* p = (char*)d_ws;
    __bf16* Hb   = (__bf16*)p; p += (size_t)N_NODES * N_EDGES * 2;   // 67.1 MB
    __bf16* HbT  = (__bf16*)p; p += (size_t)N_EDGES * N_NODES * 2;   // 67.1 MB
    __bf16* xb   = (__bf16*)p; p += (size_t)BATCH * N_NODES * F_INS * 2; // 8.4 MB
    __bf16* WbT  = (__bf16*)p; p += (size_t)HDIM * F_INS * 2;        // 0.26 MB
    __bf16* WhbT = (__bf16*)p; p += (size_t)CCOMB * N_NODES * 2;     // 16.8 MB
    __bf16* mwT  = (__bf16*)p; p += (size_t)CCOMB * N_EDGES * 2;     // 8.4 MB
    float*  Wa   = (float*)p;  p += (size_t)F_INS * HEADS * 4;
    float*  av   = (float*)p;  p += (size_t)BATCH * N_NODES * HEADS * 4;
    float*  ae   = (float*)p;  p += (size_t)16 * N_EDGES * 4;        // logits->softmax in place
    float*  acc1 = (float*)p;  p += (size_t)4 * CCOMB * N_EDGES * 4; // 67.1 MB: 4 fp32 slabs
    // plog (32 nb x 16 q x 4096 e fp32 = 8 MB) overlays acc1: its lifetime
    // (convert_H -> reduce_logits) ends before gemm256<0> first writes acc1.
    float*  plog = acc1;

    wbt_kernel<<<dim3(HDIM * F_INS / 256), 256, 0, stream>>>(W, WbT);
    wa_kernel<<<dim3(8), 256, 0, stream>>>(W, a, Wa);
    av_kernel<<<dim3(BATCH * N_NODES / 32), 256, 0, stream>>>(x, Wa, av, xb);
    convert_H_logits_kernel<<<dim3(N_EDGES / 128, N_NODES / 256), 256, 0, stream>>>(
        H, av, Hb, HbT, plog);
    reduce_logits_kernel<<<dim3(256), 256, 0, stream>>>(plog, ae);
    softmax_kernel<<<dim3(16), 256, 0, stream>>>(ae);

    // WhbT[b*512+c][n] = sum_f WbT[c][f] * xb[b][n][f]   (K=256, m97 structure is fine)
    gemm_bt<0><<<dim3(64, 4, 2), 256, 0, stream>>>(
        WbT, xb, F_INS, F_INS, F_INS,
        0, (size_t)N_NODES * F_INS, (size_t)HDIM * N_NODES,
        WhbT, N_NODES, nullptr);

    // acc1 slab z: [c][e] = sum over n-slab of WhbT[c][n]*HbT[e][n]
    // 8-phase 256x256; K=8192 -> 4 slabs of 2048; 256 blocks; SWZ=2 XCD remap
    gemm256<2><<<dim3(16, 4, 4), 512, 0, stream>>>(
        WhbT, HbT, N_NODES, N_NODES, 2048,
        2048, 2048, (size_t)CCOMB * N_EDGES,
        acc1, N_EDGES);

    // mwT[c][e] = bf16( (sum of 4 slabs) * ae[c>>6][e] )
    scale1_kernel<<<dim3(CCOMB * N_EDGES / 4 / 256), 256, 0, stream>>>(acc1, ae, mwT);

    // out-slab z (into acc1, now free): [n][c] = sum over e-slab of Hb[n][e]*mwT[c][e]
    // K=4096 -> 2 slabs of 2048; 256 blocks; SWZ=1 XCD remap
    gemm256<1><<<dim3(4, 32, 2), 512, 0, stream>>>(
        Hb, mwT, N_EDGES, N_EDGES, 2048,
        2048, 2048, (size_t)N_NODES * CCOMB,
        acc1, CCOMB);

    // out[b][n][hd] = slab0 + slab1 (scatter to final layout)
    reduce2_kernel<<<dim3(N_NODES * CCOMB / 4 / 256), 256, 0, stream>>>(acc1, out);
}

// Round 8
// 461.779 us; speedup vs baseline: 1.5270x; 1.0280x over previous
//
#include <hip/hip_runtime.h>

#define N_NODES 8192
#define N_EDGES 4096
#define F_INS   256
#define HEADS   8
#define DOUT    64
#define HDIM    512   // HEADS*DOUT
#define CCOMB   1024  // 2*HDIM (both batches as columns)
#define BATCH   2

typedef __bf16 bf16x8 __attribute__((ext_vector_type(8)));
typedef __bf16 bf16x4 __attribute__((ext_vector_type(4)));
typedef float  f32x4  __attribute__((ext_vector_type(4)));

// async 16B global->LDS (wave-uniform LDS base + lane*16)
__device__ __forceinline__ void gld_lds16(const __bf16* g, __bf16* l) {
    __builtin_amdgcn_global_load_lds(
        (const __attribute__((address_space(1))) void*)g,
        (__attribute__((address_space(3))) void*)l, 16, 0, 0);
}

// ---------- streaming: Hb = bf16(H) + plog partials (fp32 exact, atomic-free) ----
// grid (E/128, N/256), 256 thr. NO barriers in the main loop (lav read-only
// after one sync) -> waves run free, latency hidden by TLP. v5: transpose
// moved to its own kernel (3 fused variants all plateaued ~105us on barriers).
__launch_bounds__(256)
__global__ void convert_hb_logits_kernel(const float* __restrict__ H,
                                         const float* __restrict__ av,
                                         __bf16* __restrict__ Hb,
                                         float* __restrict__ plog) {
    __shared__ __align__(16) float smem[8192];  // 32 KB
    float* lav = smem;   // [256][16] (16 KB)
    float* red = smem;   // [4][16][128] overlay after main loop

    int t = threadIdx.x;
    int e0 = blockIdx.x * 128;
    int n0 = blockIdx.y * 256;
    int equad = t & 31, r0 = t >> 5;
    int lane = t & 63, wv = t >> 6;

    // lav[n][q]: q = b*8+h
    for (int p = t; p < 4096; p += 256) {
        int n = p >> 4, q = p & 15, b = q >> 3, h = q & 7;
        lav[p] = av[(size_t)b * (N_NODES * 8) + (size_t)(n0 + n) * 8 + h];
    }
    __syncthreads();  // lav ready; no further barriers until reduce

    const float* hbase = H + (size_t)n0 * N_EDGES + e0 + equad * 4;
    __bf16* hb_base = Hb + (size_t)n0 * N_EDGES + e0 + equad * 4;

    f32x4 acc[4][4] = {};  // [ec][qq], components = qi

    for (int g = 0; g < 8; ++g) {
#pragma unroll
        for (int k = 0; k < 4; ++k) {
            int n = g * 32 + r0 + 8 * k;
            float4 vv = *(const float4*)(hbase + (size_t)n * N_EDGES);
            const f32x4* lrow = (const f32x4*)&lav[n * 16];
#pragma unroll
            for (int qq = 0; qq < 4; ++qq) {
                f32x4 l = lrow[qq];
                acc[0][qq] += l * vv.x;
                acc[1][qq] += l * vv.y;
                acc[2][qq] += l * vv.z;
                acc[3][qq] += l * vv.w;
            }
            bf16x4 hb;
            hb[0] = (__bf16)vv.x; hb[1] = (__bf16)vv.y;
            hb[2] = (__bf16)vv.z; hb[3] = (__bf16)vv.w;
            *(bf16x4*)(hb_base + (size_t)n * N_EDGES) = hb;
        }
    }

    // logits reduce: intra-wave (r0 pairs) via shfl_xor(32)
#pragma unroll
    for (int ec = 0; ec < 4; ++ec)
#pragma unroll
        for (int qq = 0; qq < 4; ++qq)
#pragma unroll
            for (int qi = 0; qi < 4; ++qi)
                acc[ec][qq][qi] += __shfl_xor(acc[ec][qq][qi], 32, 64);

    __syncthreads();  // all lav reads done before red overlay
    if (lane < 32) {
        // red[wv][q][el]: f32x4 over ec at el = equad*4 -> conflict-free b128
#pragma unroll
        for (int qq = 0; qq < 4; ++qq)
#pragma unroll
            for (int qi = 0; qi < 4; ++qi) {
                f32x4 tmp = {acc[0][qq][qi], acc[1][qq][qi],
                             acc[2][qq][qi], acc[3][qq][qi]};
                *(f32x4*)&red[wv * 2048 + (qq * 4 + qi) * 128 + equad * 4] = tmp;
            }
    }
    __syncthreads();
#pragma unroll
    for (int s = 0; s < 8; ++s) {
        int id = s * 256 + t;  // 2048 = 16 q x 128 el
        int q = id >> 7, el = id & 127;
        float sum = red[q * 128 + el] + red[2048 + q * 128 + el] +
                    red[4096 + q * 128 + el] + red[6144 + q * 128 + el];
        plog[((size_t)blockIdx.y * 16 + q) * N_EDGES + e0 + el] = sum;
    }
}

// ---------- HbT[e][n] = Hb[n][e]  (bf16 64x64 tile transpose) ----------
// grid (E/64, N/64) = 8192 blocks. [64][65] +1-pad LDS, scalar b16 both LDS
// sides (~2-way alias = free), bf16x8 global load/store. One barrier.
__launch_bounds__(256)
__global__ void transpose_hb_kernel(const __bf16* __restrict__ Hb,
                                    __bf16* __restrict__ HbT) {
    __shared__ __bf16 tile[64][65];
    int t = threadIdx.x;
    int e0 = blockIdx.x * 64;
    int n0 = blockIdx.y * 64;
    int oct = t & 7, rq = t >> 3;  // rq in [0,32)
#pragma unroll
    for (int p = 0; p < 2; ++p) {
        int rr = rq + 32 * p;  // node row within tile
        bf16x8 v = *(const bf16x8*)(Hb + (size_t)(n0 + rr) * N_EDGES + e0 + oct * 8);
#pragma unroll
        for (int j = 0; j < 8; ++j) tile[oct * 8 + j][rr] = v[j];
    }
    __syncthreads();
#pragma unroll
    for (int p = 0; p < 2; ++p) {
        int er = rq + 32 * p;  // edge row within tile
        bf16x8 w;
#pragma unroll
        for (int j = 0; j < 8; ++j) w[j] = tile[er][oct * 8 + j];
        *(bf16x8*)(HbT + (size_t)(e0 + er) * N_NODES + n0 + oct * 8) = w;
    }
}

// ---------- logits[q][e] = sum_nb plog[nb][q][e] ----------
__launch_bounds__(256)
__global__ void reduce_logits_kernel(const float* __restrict__ plog,
                                     float* __restrict__ logits) {
    int id = blockIdx.x * 256 + threadIdx.x;  // 65536 = 16 q x 4096 e
    int q = id >> 12, e = id & 4095;
    float s = 0.f;
#pragma unroll
    for (int nb = 0; nb < 32; ++nb)
        s += plog[((size_t)nb * 16 + q) * N_EDGES + e];
    logits[(size_t)q * N_EDGES + e] = s;
}

// ---------- W (fp32 F_INS x HDIM) -> WbT (bf16 HDIM x F_INS) ----------
__launch_bounds__(256)
__global__ void wbt_kernel(const float* __restrict__ W, __bf16* __restrict__ WbT) {
    int i = blockIdx.x * 256 + threadIdx.x;  // 512*256 = 131072
    int c = i >> 8, f = i & 255;
    WbT[i] = (__bf16)W[(size_t)f * HDIM + c];
}

// ---------- Wa[f][h] = sum_d W[f][h*64+d] * a[d]  (fp32, exact path for av) ----------
__launch_bounds__(256)
__global__ void wa_kernel(const float* __restrict__ W, const float* __restrict__ a,
                          float* __restrict__ Wa) {
    int i = blockIdx.x * 256 + threadIdx.x;  // 2048
    if (i >= F_INS * HEADS) return;
    int f = i >> 3, h = i & 7;
    float s = 0.f;
#pragma unroll 8
    for (int d = 0; d < DOUT; ++d) s += W[(size_t)f * HDIM + h * DOUT + d] * a[d];
    Wa[i] = s;
}

// ---------- fused: av = leaky_relu(x . Wa) fp32  +  xb = bf16(x) ----------
__launch_bounds__(256)
__global__ void av_kernel(const float* __restrict__ x, const float* __restrict__ Wa,
                          float* __restrict__ av, __bf16* __restrict__ xb) {
    __shared__ float lx[32][257];
    __shared__ float lwa[F_INS * HEADS];
    int t = threadIdx.x;
    size_t row0 = (size_t)blockIdx.x * 32;  // rows = b*8192+n, 16384 total
    for (int p = t; p < F_INS * HEADS; p += 256) lwa[p] = Wa[p];
#pragma unroll
    for (int p = 0; p < 32; ++p) {
        float v = x[(row0 + p) * F_INS + t];
        lx[p][t] = v;
        xb[(row0 + p) * F_INS + t] = (__bf16)v;
    }
    __syncthreads();
    int r = t >> 3, h = t & 7;
    float acc = 0.f;
#pragma unroll 8
    for (int f = 0; f < F_INS; ++f) acc += lx[r][f] * lwa[f * 8 + h];
    av[(row0 + r) * 8 + h] = acc > 0.f ? acc : 0.2f * acc;
}

// ---------- softmax over e for each of 16 (b,h) rows, in place ----------
__launch_bounds__(256)
__global__ void softmax_kernel(float* __restrict__ logits) {
    __shared__ float red[4];
    __shared__ float reds[4];
    int t = threadIdx.x;
    float* row = logits + (size_t)blockIdx.x * N_EDGES;
    float mx = -1e30f;
    for (int i = t; i < N_EDGES; i += 256) mx = fmaxf(mx, row[i]);
#pragma unroll
    for (int o = 32; o > 0; o >>= 1) mx = fmaxf(mx, __shfl_xor(mx, o, 64));
    if ((t & 63) == 0) red[t >> 6] = mx;
    __syncthreads();
    mx = fmaxf(fmaxf(red[0], red[1]), fmaxf(red[2], red[3]));
    float s = 0.f;
    for (int i = t; i < N_EDGES; i += 256) {
        float v = expf(row[i] - mx);
        row[i] = v;
        s += v;
    }
#pragma unroll
    for (int o = 32; o > 0; o >>= 1) s += __shfl_xor(s, o, 64);
    if ((t & 63) == 0) reds[t >> 6] = s;
    __syncthreads();
    float inv = 1.0f / (reds[0] + reds[1] + reds[2] + reds[3]);
    for (int i = t; i < N_EDGES; i += 256) row[i] *= inv;
}

// ---------- 128x128 bf16 MFMA GEMM (m97 structure) — used only for the small K=256
// WhbT GEMM. MODE 0: store bf16 to outB[gm*ldo+gc] (+out_z per z).
template <int MODE>
__launch_bounds__(256, 4)
__global__ void gemm_bt(const __bf16* __restrict__ A, const __bf16* __restrict__ BT,
                        int lda, int ldbt, int K,
                        size_t a_bz, size_t bt_bz, size_t out_z,
                        __bf16* __restrict__ outB, int ldo,
                        float* __restrict__ outF) {
    __shared__ __bf16 AsF[8192];
    __shared__ __bf16 BsF[8192];
    int t = threadIdx.x;
    int bz = blockIdx.z;
    A  += (size_t)bz * a_bz;
    BT += (size_t)bz * bt_bz;
    if (MODE == 0) outB += (size_t)bz * out_z;
    if (MODE == 1) outF += (size_t)bz * out_z;
    size_t m0 = (size_t)blockIdx.y * 128;
    size_t n0 = (size_t)blockIdx.x * 128;

    int lane = t & 63, wv = t >> 6;
    int ln = lane & 15, lk = lane >> 4;

    const __bf16* pA[4]; const __bf16* pB[4];
    __bf16* lA[4]; __bf16* lB[4];
#pragma unroll
    for (int p = 0; p < 4; ++p) {
        int bid = wv * 4 + p;
        int mb = bid >> 1, kb = bid & 1;
        pA[p] = A + (m0 + mb * 16 + ln) * (size_t)lda + kb * 32 + lk * 8;
        pB[p] = BT + (n0 + mb * 16 + ln) * (size_t)ldbt + kb * 32 + lk * 8;
        lA[p] = &AsF[bid * 512];
        lB[p] = &BsF[bid * 512];
    }

    int wm16 = (wv & 1) * 4, wn16 = (wv >> 1) * 4;
    f32x4 acc[4][4] = {};

    for (int k0 = 0; k0 < K; k0 += 64) {
        __syncthreads();
#pragma unroll
        for (int p = 0; p < 4; ++p) gld_lds16(pA[p] + k0, lA[p]);
#pragma unroll
        for (int p = 0; p < 4; ++p) gld_lds16(pB[p] + k0, lB[p]);
        __syncthreads();
#pragma unroll
        for (int ksb = 0; ksb < 2; ++ksb) {
            bf16x8 af[4], bfr[4];
#pragma unroll
            for (int i = 0; i < 4; ++i)
                af[i] = *(const bf16x8*)&AsF[((wm16 + i) * 2 + ksb) * 512 + lane * 8];
#pragma unroll
            for (int j = 0; j < 4; ++j)
                bfr[j] = *(const bf16x8*)&BsF[((wn16 + j) * 2 + ksb) * 512 + lane * 8];
#pragma unroll
            for (int i = 0; i < 4; ++i)
#pragma unroll
                for (int j = 0; j < 4; ++j)
                    acc[i][j] = __builtin_amdgcn_mfma_f32_16x16x32_bf16(
                        af[i], bfr[j], acc[i][j], 0, 0, 0);
        }
    }

    int wm = (wv & 1) * 64, wn = (wv >> 1) * 64;
#pragma unroll
    for (int i = 0; i < 4; ++i)
#pragma unroll
        for (int j = 0; j < 4; ++j)
#pragma unroll
            for (int rg = 0; rg < 4; ++rg) {
                int gm = (int)m0 + wm + i * 16 + lk * 4 + rg;
                int gc = (int)n0 + wn + j * 16 + ln;
                float v = acc[i][j][rg];
                if (MODE == 0) {
                    outB[(size_t)gm * ldo + gc] = (__bf16)v;
                } else if (MODE == 1) {
                    outF[(size_t)gm * ldo + gc] = v;
                } else {
                    outF[(size_t)(gc >> 9) * ((size_t)N_NODES * HDIM) +
                         (size_t)gm * HDIM + (gc & 511)] = v;
                }
            }
}

// ---------- 256x256 8-phase deep-pipelined bf16 GEMM (T3+T4+T5) ----------
// BK=64, 8 waves, 2x64KB LDS double buffer, fragment-major. 4 phases/K-tile:
// {12 ds_read quadrant, stage 2 frags of tile t+1, vmcnt(4), s_barrier,
// 16 MFMA in setprio}. See round-4 notes for the stage-pair/vmcnt proof.
// SWZ=1: XCD remap for grid (4,32,2). SWZ=2: XCD remap for grid (16,4,4) —
// each XCD owns 2 (by,bz) A-panels (same bz) x all 16 bx: A dedups in-XCD,
// concurrent by-pairs dedup B panels in L2.
template <int SWZ>
__launch_bounds__(512, 2)
__global__ void gemm256(const __bf16* __restrict__ A, const __bf16* __restrict__ BT,
                        int lda, int ldbt, int K,
                        size_t a_bz, size_t bt_bz, size_t out_z,
                        float* __restrict__ outF, int ldo) {
    __shared__ __bf16 lds[2 * 2 * 32 * 512];  // [buf][op][frag][512], 128 KB
#define LOFF(b, op, fr) ((((b) * 2 + (op)) * 32 + (fr)) * 512)
    int bx, by, bz;
    if (SWZ == 1) {
        int g = (int)blockIdx.x + 4 * ((int)blockIdx.y + 32 * (int)blockIdx.z);
        int xcd = g & 7, j = g >> 3;
        int l = (j & 3) + 4 * xcd + 32 * (j >> 2);
        bx = l & 3; by = (l >> 2) & 31; bz = l >> 7;
    } else if (SWZ == 2) {
        int g = (int)blockIdx.x + 16 * ((int)blockIdx.y + 4 * (int)blockIdx.z);
        int xcd = g & 7, j = g >> 3;        // j in [0,32)
        int pan = xcd * 2 + (j >> 4);       // panel = bz*4+by
        bx = j & 15; by = pan & 3; bz = pan >> 2;
    } else {
        bx = blockIdx.x; by = blockIdx.y; bz = blockIdx.z;
    }
    A    += (size_t)bz * a_bz;
    BT   += (size_t)bz * bt_bz;
    outF += (size_t)bz * out_z;
    size_t m0 = (size_t)by * 256;
    size_t n0 = (size_t)bx * 256;

    int t = threadIdx.x;
    int lane = t & 63, wv = t >> 6;     // 8 waves
    int ln = lane & 15, lk = lane >> 4;
    int wmf = (wv >> 2) * 8;            // wave m-frag base (0 or 8)
    int wnf = (wv & 3) * 4;             // wave n-frag base (0,4,8,12)

    // staging assignment (per wave): one mb/nb per pair, both ks each
    int mbA0 = (wv < 4) ? wv : wv + 4;       // pair0: A-mhalf0 (mb 0-3, 8-11)
    int mbA1 = (wv < 4) ? wv + 4 : wv + 8;   // pair3: A-mhalf1 (mb 4-7, 12-15)
    int nbB0 = (wv >> 1) * 4 + (wv & 1);     // pair1: B-nhalf0 (nb 0,1,4,5,...)
    int nbB1 = nbB0 + 2;                     // pair2: B-nhalf1 (nb 2,3,6,7,...)
    const __bf16* gA0 = A + (m0 + mbA0 * 16 + ln) * (size_t)lda + lk * 8;
    const __bf16* gA1 = A + (m0 + mbA1 * 16 + ln) * (size_t)lda + lk * 8;
    const __bf16* gB0 = BT + (n0 + nbB0 * 16 + ln) * (size_t)ldbt + lk * 8;
    const __bf16* gB1 = BT + (n0 + nbB1 * 16 + ln) * (size_t)ldbt + lk * 8;

    int NT = K >> 6;  // K-tiles of 64

    // prologue: stage tile 0 (buf 0), pair order 0,1,2,3
    gld_lds16(gA0, &lds[LOFF(0, 0, mbA0 * 2 + 0)]);
    gld_lds16(gA0 + 32, &lds[LOFF(0, 0, mbA0 * 2 + 1)]);
    gld_lds16(gB0, &lds[LOFF(0, 1, nbB0 * 2 + 0)]);
    gld_lds16(gB0 + 32, &lds[LOFF(0, 1, nbB0 * 2 + 1)]);
    gld_lds16(gB1, &lds[LOFF(0, 1, nbB1 * 2 + 0)]);
    gld_lds16(gB1 + 32, &lds[LOFF(0, 1, nbB1 * 2 + 1)]);
    gld_lds16(gA1, &lds[LOFF(0, 0, mbA1 * 2 + 0)]);
    gld_lds16(gA1 + 32, &lds[LOFF(0, 0, mbA1 * 2 + 1)]);
    asm volatile("s_waitcnt vmcnt(4)" ::: "memory");  // pair0+pair1 landed
    __builtin_amdgcn_s_barrier();
    __builtin_amdgcn_sched_barrier(0);

    f32x4 acc[8][4] = {};

#define PHASE(TL, P, DO_STAGE, VMN)                                            \
    {                                                                          \
        const int c_ = (TL) & 1;                                               \
        bf16x8 af_[4][2], bf_[2][2];                                           \
        _Pragma("unroll") for (int mi = 0; mi < 4; ++mi)                       \
            _Pragma("unroll") for (int ks = 0; ks < 2; ++ks)                   \
                af_[mi][ks] = *(const bf16x8*)&lds[                            \
                    LOFF(c_, 0, (wmf + ((P) >> 1) * 4 + mi) * 2 + ks) + lane * 8]; \
        _Pragma("unroll") for (int nj = 0; nj < 2; ++nj)                       \
            _Pragma("unroll") for (int ks = 0; ks < 2; ++ks)                   \
                bf_[nj][ks] = *(const bf16x8*)&lds[                            \
                    LOFF(c_, 1, (wnf + ((P) & 1) * 2 + nj) * 2 + ks) + lane * 8]; \
        if (DO_STAGE) {                                                        \
            const int ub_ = ((TL) + 1) & 1;                                    \
            const int ko_ = ((TL) + 1) * 64;                                   \
            if ((P) == 0) {                                                    \
                gld_lds16(gA0 + ko_, &lds[LOFF(ub_, 0, mbA0 * 2 + 0)]);        \
                gld_lds16(gA0 + ko_ + 32, &lds[LOFF(ub_, 0, mbA0 * 2 + 1)]);   \
            } else if ((P) == 1) {                                             \
                gld_lds16(gB0 + ko_, &lds[LOFF(ub_, 1, nbB0 * 2 + 0)]);        \
                gld_lds16(gB0 + ko_ + 32, &lds[LOFF(ub_, 1, nbB0 * 2 + 1)]);   \
            } else if ((P) == 2) {                                             \
                gld_lds16(gB1 + ko_, &lds[LOFF(ub_, 1, nbB1 * 2 + 0)]);        \
                gld_lds16(gB1 + ko_ + 32, &lds[LOFF(ub_, 1, nbB1 * 2 + 1)]);   \
            } else {                                                           \
                gld_lds16(gA1 + ko_, &lds[LOFF(ub_, 0, mbA1 * 2 + 0)]);        \
                gld_lds16(gA1 + ko_ + 32, &lds[LOFF(ub_, 0, mbA1 * 2 + 1)]);   \
            }                                                                  \
        }                                                                      \
        if ((VMN) >= 0)                                                        \
            asm volatile("s_waitcnt vmcnt(%0)" ::"i"(VMN) : "memory");         \
        __builtin_amdgcn_s_barrier();                                          \
        __builtin_amdgcn_sched_barrier(0);                                     \
        __builtin_amdgcn_s_setprio(1);                                         \
        _Pragma("unroll") for (int mi = 0; mi < 4; ++mi)                       \
            _Pragma("unroll") for (int nj = 0; nj < 2; ++nj)                   \
                _Pragma("unroll") for (int ks = 0; ks < 2; ++ks)               \
                    acc[((P) >> 1) * 4 + mi][((P) & 1) * 2 + nj] =             \
                        __builtin_amdgcn_mfma_f32_16x16x32_bf16(               \
                            af_[mi][ks], bf_[nj][ks],                          \
                            acc[((P) >> 1) * 4 + mi][((P) & 1) * 2 + nj],      \
                            0, 0, 0);                                          \
        __builtin_amdgcn_s_setprio(0);                                         \
    }

    for (int tl = 0; tl < NT - 1; ++tl) {
        PHASE(tl, 0, 1, 4);
        PHASE(tl, 1, 1, 4);
        PHASE(tl, 2, 1, 4);
        PHASE(tl, 3, 1, 4);
    }
    // epilogue tile NT-1: no staging; drain 2 -> 0
    PHASE(NT - 1, 0, 0, 2);
    PHASE(NT - 1, 1, 0, 0);
    PHASE(NT - 1, 2, 0, -1);
    PHASE(NT - 1, 3, 0, -1);
#undef PHASE
#undef LOFF

    int wm = (wv >> 2) * 128, wn = (wv & 3) * 64;
#pragma unroll
    for (int i = 0; i < 8; ++i)
#pragma unroll
        for (int j = 0; j < 4; ++j)
#pragma unroll
            for (int rg = 0; rg < 4; ++rg) {
                int gm = (int)m0 + wm + i * 16 + lk * 4 + rg;
                int gc = (int)n0 + wn + j * 16 + ln;
                outF[(size_t)gm * ldo + gc] = acc[i][j][rg];
            }
}

// ---------- mwT = bf16( (slab0+slab1+slab2+slab3) * ae ) ----------
__launch_bounds__(256)
__global__ void scale1_kernel(const float* __restrict__ acc1, const float* __restrict__ ae,
                              __bf16* __restrict__ mwT) {
    int i = blockIdx.x * 256 + threadIdx.x;  // float4 index, 1M total
    size_t base = (size_t)i * 4;
    int c = (int)(base >> 12);
    int e = (int)(base & 4095);
    const size_t slab = (size_t)CCOMB * N_EDGES / 4;  // float4 units
    float4 s0 = ((const float4*)acc1)[i];
    float4 s1 = ((const float4*)acc1)[i + slab];
    float4 s2 = ((const float4*)acc1)[i + 2 * slab];
    float4 s3 = ((const float4*)acc1)[i + 3 * slab];
    float4 a4 = *(const float4*)(ae + ((size_t)(c >> 6) << 12) + e);
    bf16x4 o;
    o.x = (__bf16)((s0.x + s1.x + s2.x + s3.x) * a4.x);
    o.y = (__bf16)((s0.y + s1.y + s2.y + s3.y) * a4.y);
    o.z = (__bf16)((s0.z + s1.z + s2.z + s3.z) * a4.z);
    o.w = (__bf16)((s0.w + s1.w + s2.w + s3.w) * a4.w);
    ((bf16x4*)mwT)[i] = o;
}

// ---------- out[b][n][hd] = slab0[n][c] + slab1[n][c],  c = b*512+hd ----------
__launch_bounds__(256)
__global__ void reduce2_kernel(const float* __restrict__ s, float* __restrict__ out) {
    int i = blockIdx.x * 256 + threadIdx.x;      // float4 units: 8192*1024/4
    size_t base = (size_t)i * 4;
    int m = (int)(base >> 10);
    int c = (int)(base & 1023);
    const size_t slab = (size_t)N_NODES * CCOMB / 4;  // float4 units
    float4 a = ((const float4*)s)[i];
    float4 b = ((const float4*)s)[i + slab];
    float4 o;
    o.x = a.x + b.x; o.y = a.y + b.y; o.z = a.z + b.z; o.w = a.w + b.w;
    *(float4*)&out[(size_t)(c >> 9) * ((size_t)N_NODES * HDIM) +
                   (size_t)m * HDIM + (c & 511)] = o;
}

extern "C" void kernel_launch(void* const* d_in, const int* in_sizes, int n_in,
                              void* d_out, int out_size, void* d_ws, size_t ws_size,
                              hipStream_t stream) {
    const float* x = (const float*)d_in[0];
    const float* H = (const float*)d_in[1];
    const float* W = (const float*)d_in[2];
    const float* a = (const float*)d_in[3];
    float* out = (float*)d_out;

    // workspace carve-up (~235 MB)
    char* p = (char*)d_ws;
    __bf16* Hb   = (__bf16*)p; p += (size_t)N_NODES * N_EDGES * 2;   // 67.1 MB
    __bf16* HbT  = (__bf16*)p; p += (size_t)N_EDGES * N_NODES * 2;   // 67.1 MB
    __bf16* xb   = (__bf16*)p; p += (size_t)BATCH * N_NODES * F_INS * 2; // 8.4 MB
    __bf16* WbT  = (__bf16*)p; p += (size_t)HDIM * F_INS * 2;        // 0.26 MB
    __bf16* WhbT = (__bf16*)p; p += (size_t)CCOMB * N_NODES * 2;     // 16.8 MB
    __bf16* mwT  = (__bf16*)p; p += (size_t)CCOMB * N_EDGES * 2;     // 8.4 MB
    float*  Wa   = (float*)p;  p += (size_t)F_INS * HEADS * 4;
    float*  av   = (float*)p;  p += (size_t)BATCH * N_NODES * HEADS * 4;
    float*  ae   = (float*)p;  p += (size_t)16 * N_EDGES * 4;        // logits->softmax in place
    float*  acc1 = (float*)p;  p += (size_t)4 * CCOMB * N_EDGES * 4; // 67.1 MB: 4 fp32 slabs
    // plog (32 nb x 16 q x 4096 e fp32 = 8 MB) overlays acc1: its lifetime
    // (convert -> reduce_logits) ends before gemm256<0> first writes acc1.
    float*  plog = acc1;

    wbt_kernel<<<dim3(HDIM * F_INS / 256), 256, 0, stream>>>(W, WbT);
    wa_kernel<<<dim3(8), 256, 0, stream>>>(W, a, Wa);
    av_kernel<<<dim3(BATCH * N_NODES / 32), 256, 0, stream>>>(x, Wa, av, xb);
    convert_hb_logits_kernel<<<dim3(N_EDGES / 128, N_NODES / 256), 256, 0, stream>>>(
        H, av, Hb, plog);
    transpose_hb_kernel<<<dim3(N_EDGES / 64, N_NODES / 64), 256, 0, stream>>>(Hb, HbT);
    reduce_logits_kernel<<<dim3(256), 256, 0, stream>>>(plog, ae);
    softmax_kernel<<<dim3(16), 256, 0, stream>>>(ae);

    // WhbT[b*512+c][n] = sum_f WbT[c][f] * xb[b][n][f]   (K=256, m97 structure is fine)
    gemm_bt<0><<<dim3(64, 4, 2), 256, 0, stream>>>(
        WbT, xb, F_INS, F_INS, F_INS,
        0, (size_t)N_NODES * F_INS, (size_t)HDIM * N_NODES,
        WhbT, N_NODES, nullptr);

    // acc1 slab z: [c][e] = sum over n-slab of WhbT[c][n]*HbT[e][n]
    // 8-phase 256x256; K=8192 -> 4 slabs of 2048; 256 blocks; SWZ=2 XCD remap
    gemm256<2><<<dim3(16, 4, 4), 512, 0, stream>>>(
        WhbT, HbT, N_NODES, N_NODES, 2048,
        2048, 2048, (size_t)CCOMB * N_EDGES,
        acc1, N_EDGES);

    // mwT[c][e] = bf16( (sum of 4 slabs) * ae[c>>6][e] )
    scale1_kernel<<<dim3(CCOMB * N_EDGES / 4 / 256), 256, 0, stream>>>(acc1, ae, mwT);

    // out-slab z (into acc1, now free): [n][c] = sum over e-slab of Hb[n][e]*mwT[c][e]
    // K=4096 -> 2 slabs of 2048; 256 blocks; SWZ=1 XCD remap
    gemm256<1><<<dim3(4, 32, 2), 512, 0, stream>>>(
        Hb, mwT, N_EDGES, N_EDGES, 2048,
        2048, 2048, (size_t)N_NODES * CCOMB,
        acc1, CCOMB);

    // out[b][n][hd] = slab0 + slab1 (scatter to final layout)
    reduce2_kernel<<<dim3(N_NODES * CCOMB / 4 / 256), 256, 0, stream>>>(acc1, out);
}